// Round 8
// baseline (978.626 us; speedup 1.0000x reference)
//
#include <hip/hip_runtime.h>

typedef __bf16 bf16;
typedef __attribute__((ext_vector_type(8))) __bf16 bf16x8;
typedef __attribute__((ext_vector_type(4))) __bf16 bf16x4;
typedef __attribute__((ext_vector_type(4))) float f32x4;

#define N_TOK 16384
#define DMODEL 1024
#define FDIM 4096
#define NHEAD 16

// ---------------------------------------------------------------- helpers
__device__ __forceinline__ void gload_lds16(const bf16* g, bf16* l) {
  __builtin_amdgcn_global_load_lds(
      (const __attribute__((address_space(1))) void*)g,
      (__attribute__((address_space(3))) void*)l,
      16, 0, 0);
}

// gelu(x) = 0.5x(1+tanh(z)) = x / (1 + exp(-2z)),  z = 0.79788456(x + 0.044715x^3)
__device__ __forceinline__ float gelu_fast(float x) {
  float z2 = 1.5957691216057308f * (x + 0.044715f * x * x * x);
  return x / (1.0f + __expf(-z2));
}

// ---------------------------------------------------------------- fp32 -> bf16 copy
__global__ __launch_bounds__(256) void cvt_copy(const float* __restrict__ x,
                                                bf16* __restrict__ y) {
  size_t i = ((size_t)blockIdx.x * 256 + threadIdx.x) * 8;
  float4 a = *(const float4*)(x + i);
  float4 b = *(const float4*)(x + i + 4);
  bf16x8 o;
  o[0] = (bf16)a.x; o[1] = (bf16)a.y; o[2] = (bf16)a.z; o[3] = (bf16)a.w;
  o[4] = (bf16)b.x; o[5] = (bf16)b.y; o[6] = (bf16)b.z; o[7] = (bf16)b.w;
  *(bf16x8*)(y + i) = o;
}

// ---------------------------------------------------------------- convert+transpose
__global__ void convt(const float* __restrict__ src, bf16* __restrict__ dst,
                      int R, int C) {
  __shared__ float tile[32][33];
  int c0 = blockIdx.x * 32, r0 = blockIdx.y * 32;
  int tx = threadIdx.x, ty = threadIdx.y;
#pragma unroll
  for (int i = 0; i < 4; ++i)
    tile[ty * 4 + i][tx] = src[(size_t)(r0 + ty * 4 + i) * C + c0 + tx];
  __syncthreads();
#pragma unroll
  for (int i = 0; i < 4; ++i)
    dst[(size_t)(c0 + ty * 4 + i) * R + r0 + tx] = (bf16)tile[tx][ty * 4 + i];
}

// ---------------------------------------------------------------- read-ahead GEMM
// C[M][N] = A[M][K] @ BT[N][K]^T + bias (+res) (+gelu); output bf16.
// BM_ in {256,128}, BN=256, BK=64. 512 threads, 8 waves (2Mx4N).
// 2 LDS buffers; 4 phases/K-tile, frag ds_reads pipelined ONE PHASE AHEAD
// (reads/phase 4,8,8,4) so LDS pipe overlaps MFMA pipe. 0-conflict XOR
// swizzle (chunk^=row&7). Staging: B(t+2)@P2, A(t+2)@P3 into buf[t&1];
// counted wait = vmcnt(0) at P1-end (only t+1's 8 loads outstanding there;
// t+2's issued after -> never over-drains). Loop unrolled x2 (bL dbl-set).
template <int BM_, int RES, int GELU, int SPLIT3>  // RES: 0 none, 1 fp32, 2 bf16
__global__ __launch_bounds__(512) void gemm_c(
    const bf16* __restrict__ A, const bf16* __restrict__ BT,
    const float* __restrict__ bias, const float* __restrict__ bias2,
    const float* __restrict__ bias3, const float* __restrict__ resf,
    const bf16* __restrict__ resb, bf16* __restrict__ C,
    bf16* __restrict__ C2, bf16* __restrict__ C3,
    int M, int N, int K) {
  constexpr int ALOADS = BM_ / 64;     // gloads/thread for an A tile (4 or 2)
  constexpr int MQ = BM_ / 64;         // m-frags per quadrant (4 or 2)
  constexpr int MH = 2 * MQ;
  __shared__ alignas(16) bf16 sA[2][BM_ * 64];
  __shared__ alignas(16) bf16 sB[2][256 * 64];

  const int tid = threadIdx.x;
  const int lane = tid & 63, wv = tid >> 6;
  const int wr = wv >> 2, wc = wv & 3;       // 2 x 4 wave grid
  const int r16 = lane & 15, hk = lane >> 4;

  const int nbn = N >> 8;
  const int cpx = gridDim.x >> 3;            // grid % 8 == 0
  const int swz = ((int)blockIdx.x & 7) * cpx + ((int)blockIdx.x >> 3);
  const int row0 = (swz / nbn) * BM_, col0 = (swz % nbn) << 8;

  const bf16* Ab = A + (size_t)row0 * K;
  const bf16* Bb = BT + (size_t)col0 * K;

  // hoisted per-thread staging source bases
  const bf16* gA[ALOADS];
  const bf16* gB[4];
#pragma unroll
  for (int l = 0; l < ALOADS; ++l) {
    int g = l * 512 + tid, r = g >> 3, p = g & 7;
    gA[l] = Ab + (size_t)r * K + ((p ^ (r & 7)) << 3);
  }
#pragma unroll
  for (int l = 0; l < 4; ++l) {
    int g = l * 512 + tid, r = g >> 3, p = g & 7;
    gB[l] = Bb + (size_t)r * K + ((p ^ (r & 7)) << 3);
  }

  auto stageA = [&](int buf, int kt) {
    const size_t ko = (size_t)kt << 6;
#pragma unroll
    for (int l = 0; l < ALOADS; ++l)
      gload_lds16(gA[l] + ko, &sA[buf][(l * 512 + tid) * 8]);
  };
  auto stageB = [&](int buf, int kt) {
    const size_t ko = (size_t)kt << 6;
#pragma unroll
    for (int l = 0; l < 4; ++l)
      gload_lds16(gB[l] + ko, &sB[buf][(l * 512 + tid) * 8]);
  };
  auto frag = [&](const bf16* s, int row, int kc) -> bf16x8 {
    return *(const bf16x8*)(s + row * 64 + (kc ^ ((row & 7) * 8)));
  };

  f32x4 acc[MH][4] = {};
  bf16x8 aL[MQ][2], aH[MQ][2], bH[2][2], bLa[2][2], bLb[2][2];

  const int nt = K >> 6;                     // even (K=1024 or 4096)
  // prologue: stage tiles 0,1; wait tile0 (leave tile1 in flight); preload
  stageB(0, 0); stageA(0, 0);
  stageB(1, 1); stageA(1, 1);
  if constexpr (BM_ == 256) asm volatile("s_waitcnt vmcnt(8)" ::: "memory");
  else                      asm volatile("s_waitcnt vmcnt(6)" ::: "memory");
  __builtin_amdgcn_s_barrier();
#pragma unroll
  for (int m = 0; m < MQ; ++m)
#pragma unroll
    for (int ks = 0; ks < 2; ++ks)
      aL[m][ks] = frag(&sA[0][0], wr * (BM_ / 2) + m * 16 + r16, ks * 32 + hk * 8);
#pragma unroll
  for (int n = 0; n < 2; ++n)
#pragma unroll
    for (int ks = 0; ks < 2; ++ks)
      bLa[n][ks] = frag(&sB[0][0], wc * 64 + n * 16 + r16, ks * 32 + hk * 8);

  // one K-tile body; bLcur = this tile's bLo regs, bLnxt receives t+1's
#define TILE_BODY(t, sa, sb, saN, sbN, bLcur, bLnxt)                           \
  {                                                                            \
    const bool rd1 = ((t) + 1 < nt), st2 = ((t) + 2 < nt);                     \
    /* P0: read bH(t); MFMA Q00(aL,bLcur) */                                   \
    _Pragma("unroll") for (int n = 0; n < 2; ++n)                              \
      _Pragma("unroll") for (int ks = 0; ks < 2; ++ks)                         \
        bH[n][ks] = frag(sb, wc * 64 + (2 + n) * 16 + r16, ks * 32 + hk * 8);  \
    __builtin_amdgcn_s_barrier();                                              \
    __builtin_amdgcn_s_setprio(1);                                             \
    _Pragma("unroll") for (int ks = 0; ks < 2; ++ks)                           \
      _Pragma("unroll") for (int m = 0; m < MQ; ++m)                           \
        _Pragma("unroll") for (int n = 0; n < 2; ++n)                          \
          acc[m][n] = __builtin_amdgcn_mfma_f32_16x16x32_bf16(                 \
              bLcur[n][ks], aL[m][ks], acc[m][n], 0, 0, 0);                    \
    __builtin_amdgcn_s_setprio(0);                                             \
    __builtin_amdgcn_s_barrier();                                              \
    /* P1: read aH(t); MFMA Q01(aL,bH); vmcnt(0) completes t+1 staging */      \
    _Pragma("unroll") for (int m = 0; m < MQ; ++m)                             \
      _Pragma("unroll") for (int ks = 0; ks < 2; ++ks)                         \
        aH[m][ks] = frag(sa, wr * (BM_ / 2) + (MQ + m) * 16 + r16,             \
                         ks * 32 + hk * 8);                                    \
    __builtin_amdgcn_s_barrier();                                              \
    __builtin_amdgcn_s_setprio(1);                                             \
    _Pragma("unroll") for (int ks = 0; ks < 2; ++ks)                           \
      _Pragma("unroll") for (int m = 0; m < MQ; ++m)                           \
        _Pragma("unroll") for (int n = 0; n < 2; ++n)                          \
          acc[m][2 + n] = __builtin_amdgcn_mfma_f32_16x16x32_bf16(             \
              bH[n][ks], aL[m][ks], acc[m][2 + n], 0, 0, 0);                   \
    __builtin_amdgcn_s_setprio(0);                                             \
    asm volatile("s_waitcnt vmcnt(0)" ::: "memory");                           \
    __builtin_amdgcn_s_barrier();                                              \
    /* P2: read aLo(t+1); stage B(t+2); MFMA Q11(aH,bH) */                     \
    if (rd1) {                                                                 \
      _Pragma("unroll") for (int m = 0; m < MQ; ++m)                           \
        _Pragma("unroll") for (int ks = 0; ks < 2; ++ks)                       \
          aL[m][ks] = frag(saN, wr * (BM_ / 2) + m * 16 + r16,                 \
                           ks * 32 + hk * 8);                                  \
    }                                                                          \
    if (st2) stageB((t) & 1, (t) + 2);                                         \
    __builtin_amdgcn_s_barrier();                                              \
    __builtin_amdgcn_s_setprio(1);                                             \
    _Pragma("unroll") for (int ks = 0; ks < 2; ++ks)                           \
      _Pragma("unroll") for (int m = 0; m < MQ; ++m)                           \
        _Pragma("unroll") for (int n = 0; n < 2; ++n)                          \
          acc[MQ + m][2 + n] = __builtin_amdgcn_mfma_f32_16x16x32_bf16(        \
              bH[n][ks], aH[m][ks], acc[MQ + m][2 + n], 0, 0, 0);              \
    __builtin_amdgcn_s_setprio(0);                                             \
    __builtin_amdgcn_s_barrier();                                              \
    /* P3: read bLo(t+1)->bLnxt; stage A(t+2); MFMA Q10(aH,bLcur) */           \
    if (rd1) {                                                                 \
      _Pragma("unroll") for (int n = 0; n < 2; ++n)                            \
        _Pragma("unroll") for (int ks = 0; ks < 2; ++ks)                       \
          bLnxt[n][ks] = frag(sbN, wc * 64 + n * 16 + r16, ks * 32 + hk * 8);  \
    }                                                                          \
    if (st2) stageA((t) & 1, (t) + 2);                                         \
    __builtin_amdgcn_s_barrier();                                              \
    __builtin_amdgcn_s_setprio(1);                                             \
    _Pragma("unroll") for (int ks = 0; ks < 2; ++ks)                           \
      _Pragma("unroll") for (int m = 0; m < MQ; ++m)                           \
        _Pragma("unroll") for (int n = 0; n < 2; ++n)                          \
          acc[MQ + m][n] = __builtin_amdgcn_mfma_f32_16x16x32_bf16(            \
              bLcur[n][ks], aH[m][ks], acc[MQ + m][n], 0, 0, 0);               \
    __builtin_amdgcn_s_setprio(0);                                             \
    __builtin_amdgcn_s_barrier();                                              \
  }

  for (int it = 0; it < nt / 2; ++it) {
    const int e = 2 * it;
    TILE_BODY(e,     &sA[0][0], &sB[0][0], &sA[1][0], &sB[1][0], bLa, bLb);
    TILE_BODY(e + 1, &sA[1][0], &sB[1][0], &sA[0][0], &sB[0][0], bLb, bLa);
  }
#undef TILE_BODY

  // ---- epilogue ----
  bf16* Cp = C;
  const float* bp = bias;
  int ldc = N, colb = col0;
  if constexpr (SPLIT3) {
    int grp = col0 >> 10;
    Cp = grp == 0 ? C : (grp == 1 ? C2 : C3);
    bp = grp == 0 ? bias : (grp == 1 ? bias2 : bias3);
    ldc = 1024;
    colb = col0 & 1023;
  }
#pragma unroll
  for (int m = 0; m < MH; ++m) {
    int row = row0 + wr * (BM_ / 2) + m * 16 + r16;
#pragma unroll
    for (int n = 0; n < 4; ++n) {
      int col = colb + wc * 64 + n * 16 + hk * 4;
      f32x4 b4 = *(const f32x4*)&bp[col];
      f32x4 v;
#pragma unroll
      for (int r = 0; r < 4; ++r) v[r] = acc[m][n][r] + b4[r];
      if (RES == 1) {
        f32x4 rr = *(const f32x4*)&resf[(size_t)row * ldc + col];
#pragma unroll
        for (int r = 0; r < 4; ++r) v[r] += rr[r];
      }
      if (RES == 2) {
        bf16x4 rb = *(const bf16x4*)&resb[(size_t)row * ldc + col];
#pragma unroll
        for (int r = 0; r < 4; ++r) v[r] += (float)rb[r];
      }
      bf16x4 o;
#pragma unroll
      for (int r = 0; r < 4; ++r) {
        float x = v[r];
        if (GELU) x = gelu_fast(x);
        o[r] = (bf16)x;
      }
      *(bf16x4*)&Cp[(size_t)row * ldc + col] = o;
    }
  }
}

// ---------------------------------------------------------------- attention
// one block per (b,h); L=64, dh=64. ctx may alias q.
__global__ __launch_bounds__(256) void attn_k(
    const bf16* q, const bf16* __restrict__ k,
    const bf16* __restrict__ v, const float* __restrict__ rel,
    bf16* ctx) {
  __shared__ alignas(16) bf16 lQ[64 * 64];
  __shared__ alignas(16) bf16 lK[64 * 64];
  __shared__ alignas(16) bf16 lVt[64 * 64];
  __shared__ alignas(16) bf16 lP[4][16 * 64];
  __shared__ float lrel[128];

  const int bh = blockIdx.x;
  const int b = bh >> 4, h = bh & 15;
  const int tid = threadIdx.x;
  const size_t base = (size_t)(b * 64) * DMODEL + h * 64;

#pragma unroll
  for (int i = 0; i < 2; ++i) {
    int j = (tid >> 3) + i * 32;
    int d0 = (tid & 7) * 8;
    *(bf16x8*)&lQ[j * 64 + d0] = *(const bf16x8*)(q + base + (size_t)j * DMODEL + d0);
    *(bf16x8*)&lK[j * 64 + d0] = *(const bf16x8*)(k + base + (size_t)j * DMODEL + d0);
    bf16x8 vvv = *(const bf16x8*)(v + base + (size_t)j * DMODEL + d0);
#pragma unroll
    for (int u = 0; u < 8; ++u) lVt[(d0 + u) * 64 + j] = vvv[u];
  }
  if (tid < 127) lrel[tid] = rel[h * 127 + tid];
  __syncthreads();

  const int lane = tid & 63, w = tid >> 6;
  const int r16 = lane & 15, hk = lane >> 4;

  f32x4 s[4] = {};
#pragma unroll
  for (int dstep = 0; dstep < 2; ++dstep) {
    bf16x8 aq = *(const bf16x8*)&lQ[(w * 16 + r16) * 64 + dstep * 32 + hk * 8];
#pragma unroll
    for (int n = 0; n < 4; ++n) {
      bf16x8 bk_ = *(const bf16x8*)&lK[(n * 16 + r16) * 64 + dstep * 32 + hk * 8];
      s[n] = __builtin_amdgcn_mfma_f32_16x16x32_bf16(aq, bk_, s[n], 0, 0, 0);
    }
  }

  float p[16];
#pragma unroll
  for (int n = 0; n < 4; ++n)
#pragma unroll
    for (int r = 0; r < 4; ++r) {
      int i = w * 16 + hk * 4 + r;
      int j = n * 16 + r16;
      p[n * 4 + r] = s[n][r] * 0.125f + lrel[i - j + 63];
    }
#pragma unroll
  for (int r = 0; r < 4; ++r) {
    float m = fmaxf(fmaxf(p[r], p[4 + r]), fmaxf(p[8 + r], p[12 + r]));
#pragma unroll
    for (int off = 1; off < 16; off <<= 1) m = fmaxf(m, __shfl_xor(m, off));
    float sum = 0.f;
#pragma unroll
    for (int n = 0; n < 4; ++n) {
      p[n * 4 + r] = __expf(p[n * 4 + r] - m);
      sum += p[n * 4 + r];
    }
#pragma unroll
    for (int off = 1; off < 16; off <<= 1) sum += __shfl_xor(sum, off);
    float inv = 1.0f / sum;
#pragma unroll
    for (int n = 0; n < 4; ++n) p[n * 4 + r] *= inv;
  }
#pragma unroll
  for (int n = 0; n < 4; ++n)
#pragma unroll
    for (int r = 0; r < 4; ++r)
      lP[w][(hk * 4 + r) * 64 + n * 16 + r16] = (bf16)p[n * 4 + r];
  __syncthreads();

  f32x4 o[4] = {};
#pragma unroll
  for (int ks = 0; ks < 2; ++ks) {
    bf16x8 ap = *(const bf16x8*)&lP[w][r16 * 64 + ks * 32 + hk * 8];
#pragma unroll
    for (int n = 0; n < 4; ++n) {
      bf16x8 bv_ = *(const bf16x8*)&lVt[(n * 16 + r16) * 64 + ks * 32 + hk * 8];
      o[n] = __builtin_amdgcn_mfma_f32_16x16x32_bf16(ap, bv_, o[n], 0, 0, 0);
    }
  }
#pragma unroll
  for (int n = 0; n < 4; ++n)
#pragma unroll
    for (int r = 0; r < 4; ++r) {
      int trow = b * 64 + w * 16 + hk * 4 + r;
      ctx[(size_t)trow * DMODEL + h * 64 + n * 16 + r16] = (bf16)o[n][r];
    }
}

// ---------------------------------------------------------------- layernorm
template <int F32OUT>
__global__ __launch_bounds__(256) void layernorm_k(
    const bf16* __restrict__ x, const float* __restrict__ g,
    const float* __restrict__ be, bf16* __restrict__ ob,
    float* __restrict__ of) {
  int row = blockIdx.x * 4 + (threadIdx.x >> 6);
  int lane = threadIdx.x & 63;
  const bf16* xr = x + (size_t)row * DMODEL + lane * 16;
  bf16x8 v0 = *(const bf16x8*)xr;
  bf16x8 v1 = *(const bf16x8*)(xr + 8);
  float f[16];
#pragma unroll
  for (int j = 0; j < 8; ++j) { f[j] = (float)v0[j]; f[8 + j] = (float)v1[j]; }
  float s = 0.f, sq = 0.f;
#pragma unroll
  for (int j = 0; j < 16; ++j) { s += f[j]; sq += f[j] * f[j]; }
#pragma unroll
  for (int off = 1; off < 64; off <<= 1) {
    s += __shfl_xor(s, off);
    sq += __shfl_xor(sq, off);
  }
  float mean = s * (1.0f / DMODEL);
  float var = sq * (1.0f / DMODEL) - mean * mean;
  float rstd = rsqrtf(var + 1e-5f);
  const float* gp = g + lane * 16;
  const float* bp = be + lane * 16;
  if (F32OUT) {
    float* op = of + (size_t)row * DMODEL + lane * 16;
#pragma unroll
    for (int j = 0; j < 16; ++j)
      op[j] = (f[j] - mean) * rstd * gp[j] + bp[j];
  } else {
    bf16x8 o0, o1;
#pragma unroll
    for (int j = 0; j < 8; ++j) {
      o0[j] = (bf16)((f[j] - mean) * rstd * gp[j] + bp[j]);
      o1[j] = (bf16)((f[8 + j] - mean) * rstd * gp[8 + j] + bp[8 + j]);
    }
    bf16* op = ob + (size_t)row * DMODEL + lane * 16;
    *(bf16x8*)op = o0;
    *(bf16x8*)(op + 8) = o1;
  }
}

// ---------------------------------------------------------------- launch
extern "C" void kernel_launch(void* const* d_in, const int* in_sizes, int n_in,
                              void* d_out, int out_size, void* d_ws, size_t ws_size,
                              hipStream_t stream) {
  (void)in_sizes; (void)n_in; (void)out_size;
  const float* src = (const float*)d_in[0];
  const float* Wq  = (const float*)d_in[1];
  const float* bq  = (const float*)d_in[2];
  const float* Wk  = (const float*)d_in[3];
  const float* bk  = (const float*)d_in[4];
  const float* Wv  = (const float*)d_in[5];
  const float* bv  = (const float*)d_in[6];
  const float* Wo  = (const float*)d_in[7];
  const float* bo  = (const float*)d_in[8];
  const float* rel = (const float*)d_in[9];
  const float* W1  = (const float*)d_in[10];
  const float* b1  = (const float*)d_in[11];
  const float* W2  = (const float*)d_in[12];
  const float* b2  = (const float*)d_in[13];
  const float* g1  = (const float*)d_in[14];
  const float* be1 = (const float*)d_in[15];
  const float* g2  = (const float*)d_in[16];
  const float* be2 = (const float*)d_in[17];

  // ws plan: REGION0 = ws[0:64MiB] (srcb+qb -> hbuf -> lnout);
  // weights ws[64:88MiB] (WqT/WkT/WvT contiguous => fused QKV B matrix);
  // y2 in ws[88:120MiB] when ws_size allows, else d_out + copy-out.
  char* ws = (char*)d_ws;
  const size_t MiB = 1ull << 20;
  bf16* srcb = (bf16*)(ws + 0 * MiB);
  bf16* qb   = (bf16*)(ws + 32 * MiB);
  bf16* WqT  = (bf16*)(ws + 64 * MiB);   // [3072][1024] fused: Wq|Wk|Wv
  bf16* WkT  = (bf16*)(ws + 66 * MiB);
  bf16* WvT  = (bf16*)(ws + 68 * MiB);
  bf16* WoT  = (bf16*)(ws + 70 * MiB);
  bf16* W1T  = (bf16*)(ws + 72 * MiB);
  bf16* W2T  = (bf16*)(ws + 80 * MiB);
  bf16* hbuf = (bf16*)(ws + 0 * MiB);
  float* lnout = (float*)(ws + 0 * MiB);
  bf16* kb = (bf16*)d_out;
  bf16* vb = (bf16*)((char*)d_out + 32 * MiB);
  bf16* y1 = kb;
  bf16* xb = vb;
  const bool bigws = (ws_size >= 121 * MiB);
  bf16* y2 = bigws ? (bf16*)(ws + 88 * MiB) : kb;

  cvt_copy<<<(N_TOK * DMODEL) / 2048, 256, 0, stream>>>(src, srcb);
  dim3 tb(32, 8);
  convt<<<dim3(32, 32), tb, 0, stream>>>(Wq, WqT, 1024, 1024);
  convt<<<dim3(32, 32), tb, 0, stream>>>(Wk, WkT, 1024, 1024);
  convt<<<dim3(32, 32), tb, 0, stream>>>(Wv, WvT, 1024, 1024);
  convt<<<dim3(32, 32), tb, 0, stream>>>(Wo, WoT, 1024, 1024);
  convt<<<dim3(128, 32), tb, 0, stream>>>(W1, W1T, 1024, 4096);
  convt<<<dim3(32, 128), tb, 0, stream>>>(W2, W2T, 4096, 1024);

  // fused QKV: one GEMM, N=3072 (WqT/WkT/WvT contiguous), split outputs
  const int gQKV3 = (N_TOK / 256) * (3072 / 256);   // 64*12 = 768
  gemm_c<256, 0, 0, 1><<<gQKV3, 512, 0, stream>>>(
      srcb, WqT, bq, bk, bv, nullptr, nullptr, qb, kb, vb, N_TOK, 3072, DMODEL);

  attn_k<<<256 * NHEAD, 256, 0, stream>>>(qb, kb, vb, rel, qb);

  const int gD = (N_TOK / 256) * (DMODEL / 256);    // 256
  // y1 = ctx @ Wo + bo + src (fp32 residual) -> DO0
  gemm_c<256, 1, 0, 0><<<gD, 512, 0, stream>>>(
      qb, WoT, bo, nullptr, nullptr, src, nullptr, y1, nullptr, nullptr, N_TOK, DMODEL, DMODEL);
  // x = LN1(y1) -> DO1
  layernorm_k<0><<<N_TOK / 4, 256, 0, stream>>>(y1, g1, be1, xb, nullptr);

  // FFN in 2 chunks of 8192 rows; h (8192x4096 bf16 = 64 MiB) in REGION0
  const int CH = 8192;
  const int gF1 = (CH / 256) * (FDIM / 256);     // 32*16 = 512
  const int gF2 = (CH / 128) * (DMODEL / 256);   // 64*4  = 256  (BM=128)
  for (int c = 0; c < 2; ++c) {
    const bf16* xc = xb + (size_t)c * CH * DMODEL;
    bf16* yc = y2 + (size_t)c * CH * DMODEL;
    gemm_c<256, 0, 1, 0><<<gF1, 512, 0, stream>>>(
        xc, W1T, b1, nullptr, nullptr, nullptr, nullptr, hbuf, nullptr, nullptr, CH, FDIM, DMODEL);
    gemm_c<128, 2, 0, 0><<<gF2, 512, 0, stream>>>(
        hbuf, W2T, b2, nullptr, nullptr, nullptr, xc, yc, nullptr, nullptr, CH, DMODEL, FDIM);
  }
  if (bigws) {
    layernorm_k<1><<<N_TOK / 4, 256, 0, stream>>>(y2, g2, be2, nullptr, (float*)d_out);
  } else {
    layernorm_k<1><<<N_TOK / 4, 256, 0, stream>>>(y2, g2, be2, nullptr, lnout);
    hipMemcpyAsync(d_out, lnout, (size_t)N_TOK * DMODEL * 4, hipMemcpyDeviceToDevice, stream);
  }
}

// Round 9
// 662.317 us; speedup vs baseline: 1.4776x; 1.4776x over previous
//
#include <hip/hip_runtime.h>

typedef __bf16 bf16;
typedef __attribute__((ext_vector_type(8))) __bf16 bf16x8;
typedef __attribute__((ext_vector_type(4))) __bf16 bf16x4;
typedef __attribute__((ext_vector_type(4))) float f32x4;

#define N_TOK 16384
#define DMODEL 1024
#define FDIM 4096
#define NHEAD 16

// ---------------------------------------------------------------- helpers
__device__ __forceinline__ void gload_lds16(const bf16* g, bf16* l) {
  __builtin_amdgcn_global_load_lds(
      (const __attribute__((address_space(1))) void*)g,
      (__attribute__((address_space(3))) void*)l,
      16, 0, 0);
}

// gelu(x) = 0.5x(1+tanh(z)) = x / (1 + exp(-2z)),  z = 0.79788456(x + 0.044715x^3)
__device__ __forceinline__ float gelu_fast(float x) {
  float z2 = 1.5957691216057308f * (x + 0.044715f * x * x * x);
  return x / (1.0f + __expf(-z2));
}

// ---------------------------------------------------------------- fp32 -> bf16 copy
__global__ __launch_bounds__(256) void cvt_copy(const float* __restrict__ x,
                                                bf16* __restrict__ y) {
  size_t i = ((size_t)blockIdx.x * 256 + threadIdx.x) * 8;
  float4 a = *(const float4*)(x + i);
  float4 b = *(const float4*)(x + i + 4);
  bf16x8 o;
  o[0] = (bf16)a.x; o[1] = (bf16)a.y; o[2] = (bf16)a.z; o[3] = (bf16)a.w;
  o[4] = (bf16)b.x; o[5] = (bf16)b.y; o[6] = (bf16)b.z; o[7] = (bf16)b.w;
  *(bf16x8*)(y + i) = o;
}

// ---------------------------------------------------------------- convert+transpose
__global__ void convt(const float* __restrict__ src, bf16* __restrict__ dst,
                      int R, int C) {
  __shared__ float tile[32][33];
  int c0 = blockIdx.x * 32, r0 = blockIdx.y * 32;
  int tx = threadIdx.x, ty = threadIdx.y;
#pragma unroll
  for (int i = 0; i < 4; ++i)
    tile[ty * 4 + i][tx] = src[(size_t)(r0 + ty * 4 + i) * C + c0 + tx];
  __syncthreads();
#pragma unroll
  for (int i = 0; i < 4; ++i)
    dst[(size_t)(c0 + ty * 4 + i) * R + r0 + tx] = (bf16)tile[tx][ty * 4 + i];
}

// ---------------------------------------------------------------- balanced read-ahead GEMM
// C[M][N] = A[M][K] @ BT[N][K]^T + bias (+res) (+gelu); output bf16.
// BM_ in {256,128}, BN=256, BK=64. 512 threads, 8 waves (2Mx4N).
// 2 LDS buffers; 4 phases/K-tile, quadrant order Q00,Q01,Q11,Q10 so the
// frag sets aA(=aLo),aB(=aHi),bL,bH have disjoint live ranges:
//   ph0: rd bH(t)[4]          | MFMA Q00(aA,bL)
//   ph1: rd aB=aHi(t)[8], B#1 | MFMA Q01(aA,bH); vmcnt(2)
//   ph2: rd aA=aLo(t+1)[8], B#2+A#1 | MFMA Q11(aB,bH)
//   ph3: A#2                  | MFMA Q10(aB,bL); rd bL=bLo(t+1)[4]
// Data regs = 96 (+128 acc in AGPR) -- fits 256 unified (R8 spilled at 240+48).
// vmcnt(2) at ph1-end drains t+1's staging (age >= 2 phases), keeps
// B(t+2)#1 in flight (T4 never-drain). 0-conflict XOR swizzle (chunk^=row&7).
template <int BM_, int RES, int GELU, int SPLIT3>  // RES: 0 none, 1 fp32, 2 bf16
__global__ __launch_bounds__(512) void gemm_c(
    const bf16* __restrict__ A, const bf16* __restrict__ BT,
    const float* __restrict__ bias, const float* __restrict__ bias2,
    const float* __restrict__ bias3, const float* __restrict__ resf,
    const bf16* __restrict__ resb, bf16* __restrict__ C,
    bf16* __restrict__ C2, bf16* __restrict__ C3,
    int M, int N, int K) {
  constexpr int ALOADS = BM_ / 64;     // gloads/thread per A tile (4 or 2)
  constexpr int AH = ALOADS / 2;       // per staging half (2 or 1)
  constexpr int MQ = BM_ / 64;         // m-frags per quadrant (4 or 2)
  constexpr int MH = 2 * MQ;
  __shared__ alignas(16) bf16 sA[2][BM_ * 64];
  __shared__ alignas(16) bf16 sB[2][256 * 64];

  const int tid = threadIdx.x;
  const int lane = tid & 63, wv = tid >> 6;
  const int wr = wv >> 2, wc = wv & 3;       // 2 x 4 wave grid
  const int r16 = lane & 15, hk = lane >> 4;

  const int nbn = N >> 8;
  const int cpx = gridDim.x >> 3;            // grid % 8 == 0
  const int swz = ((int)blockIdx.x & 7) * cpx + ((int)blockIdx.x >> 3);
  const int row0 = (swz / nbn) * BM_, col0 = (swz % nbn) << 8;

  const bf16* Ab = A + (size_t)row0 * K;
  const bf16* Bb = BT + (size_t)col0 * K;

  // single per-thread staging offset; per-l parts are uniform (l*64*K)
  const int t8 = tid >> 3;                            // local row within 64-row group
  const int scol = ((tid & 7) ^ (t8 & 7)) << 3;       // inverse-swizzled source col
  const bf16* gAb = Ab + (size_t)t8 * K + scol;
  const bf16* gBb = Bb + (size_t)t8 * K + scol;

  auto stageA = [&](int buf, int kt, int half) {
#pragma unroll
    for (int l = half * AH; l < (half + 1) * AH; ++l)
      gload_lds16(gAb + (size_t)l * 64 * K + (size_t)kt * 64,
                  &sA[buf][(l * 512 + tid) * 8]);
  };
  auto stageB = [&](int buf, int kt, int half) {
#pragma unroll
    for (int l = half * 2; l < (half + 1) * 2; ++l)
      gload_lds16(gBb + (size_t)l * 64 * K + (size_t)kt * 64,
                  &sB[buf][(l * 512 + tid) * 8]);
  };
  auto frag = [&](const bf16* s, int row, int kc) -> bf16x8 {
    return *(const bf16x8*)(s + row * 64 + (kc ^ ((row & 7) * 8)));
  };

  f32x4 acc[MH][4] = {};
  bf16x8 aA[MQ][2], aB[MQ][2], bL[2][2], bH[2][2];

  const int nt = K >> 6;
  // prologue: stage tiles 0,1; drain tile 0 (keep tile 1's in flight); preload
  stageA(0, 0, 0); stageA(0, 0, 1); stageB(0, 0, 0); stageB(0, 0, 1);
  stageA(1, 1, 0); stageA(1, 1, 1); stageB(1, 1, 0); stageB(1, 1, 1);
  if constexpr (BM_ == 256) asm volatile("s_waitcnt vmcnt(8)" ::: "memory");
  else                      asm volatile("s_waitcnt vmcnt(6)" ::: "memory");
  __builtin_amdgcn_s_barrier();
#pragma unroll
  for (int m = 0; m < MQ; ++m)
#pragma unroll
    for (int ks = 0; ks < 2; ++ks)
      aA[m][ks] = frag(&sA[0][0], wr * (BM_ / 2) + m * 16 + r16, ks * 32 + hk * 8);
#pragma unroll
  for (int n = 0; n < 2; ++n)
#pragma unroll
    for (int ks = 0; ks < 2; ++ks)
      bL[n][ks] = frag(&sB[0][0], wc * 64 + n * 16 + r16, ks * 32 + hk * 8);

#define TILE_BODY(t, sa, sb, saN, sbN)                                         \
  {                                                                            \
    const bool rd1 = ((t) + 1 < nt), st2 = ((t) + 2 < nt);                     \
    /* ph0: rd bH(t); MFMA Q00(aA,bL) */                                       \
    _Pragma("unroll") for (int n = 0; n < 2; ++n)                              \
      _Pragma("unroll") for (int ks = 0; ks < 2; ++ks)                         \
        bH[n][ks] = frag(sb, wc * 64 + (2 + n) * 16 + r16, ks * 32 + hk * 8);  \
    __builtin_amdgcn_s_barrier();                                              \
    __builtin_amdgcn_s_setprio(1);                                             \
    _Pragma("unroll") for (int ks = 0; ks < 2; ++ks)                           \
      _Pragma("unroll") for (int m = 0; m < MQ; ++m)                           \
        _Pragma("unroll") for (int n = 0; n < 2; ++n)                          \
          acc[m][n] = __builtin_amdgcn_mfma_f32_16x16x32_bf16(                 \
              bL[n][ks], aA[m][ks], acc[m][n], 0, 0, 0);                       \
    __builtin_amdgcn_s_setprio(0);                                             \
    __builtin_amdgcn_s_barrier();                                              \
    /* ph1: rd aB=aHi(t); stage B(t+2)#1; MFMA Q01(aA,bH); vmcnt(2) */         \
    _Pragma("unroll") for (int m = 0; m < MQ; ++m)                             \
      _Pragma("unroll") for (int ks = 0; ks < 2; ++ks)                         \
        aB[m][ks] = frag(sa, wr * (BM_ / 2) + (MQ + m) * 16 + r16,             \
                         ks * 32 + hk * 8);                                    \
    if (st2) stageB((t) & 1, (t) + 2, 0);                                      \
    __builtin_amdgcn_s_barrier();                                              \
    __builtin_amdgcn_s_setprio(1);                                             \
    _Pragma("unroll") for (int ks = 0; ks < 2; ++ks)                           \
      _Pragma("unroll") for (int m = 0; m < MQ; ++m)                           \
        _Pragma("unroll") for (int n = 0; n < 2; ++n)                          \
          acc[m][2 + n] = __builtin_amdgcn_mfma_f32_16x16x32_bf16(             \
              bH[n][ks], aA[m][ks], acc[m][2 + n], 0, 0, 0);                   \
    __builtin_amdgcn_s_setprio(0);                                             \
    asm volatile("s_waitcnt vmcnt(2)" ::: "memory");                           \
    __builtin_amdgcn_s_barrier();                                              \
    /* ph2: rd aA=aLo(t+1); stage B#2+A#1; MFMA Q11(aB,bH) */                  \
    if (rd1) {                                                                 \
      _Pragma("unroll") for (int m = 0; m < MQ; ++m)                           \
        _Pragma("unroll") for (int ks = 0; ks < 2; ++ks)                       \
          aA[m][ks] = frag(saN, wr * (BM_ / 2) + m * 16 + r16,                 \
                           ks * 32 + hk * 8);                                  \
    }                                                                          \
    if (st2) { stageB((t) & 1, (t) + 2, 1); stageA((t) & 1, (t) + 2, 0); }     \
    __builtin_amdgcn_s_barrier();                                              \
    __builtin_amdgcn_s_setprio(1);                                             \
    _Pragma("unroll") for (int ks = 0; ks < 2; ++ks)                           \
      _Pragma("unroll") for (int m = 0; m < MQ; ++m)                           \
        _Pragma("unroll") for (int n = 0; n < 2; ++n)                          \
          acc[MQ + m][2 + n] = __builtin_amdgcn_mfma_f32_16x16x32_bf16(        \
              bH[n][ks], aB[m][ks], acc[MQ + m][2 + n], 0, 0, 0);              \
    __builtin_amdgcn_s_setprio(0);                                             \
    __builtin_amdgcn_s_barrier();                                              \
    /* ph3: stage A#2; MFMA Q10(aB,bL); then rd bL=bLo(t+1) (WAR: after) */    \
    if (st2) stageA((t) & 1, (t) + 2, 1);                                      \
    __builtin_amdgcn_s_barrier();                                              \
    __builtin_amdgcn_s_setprio(1);                                             \
    _Pragma("unroll") for (int ks = 0; ks < 2; ++ks)                           \
      _Pragma("unroll") for (int m = 0; m < MQ; ++m)                           \
        _Pragma("unroll") for (int n = 0; n < 2; ++n)                          \
          acc[MQ + m][n] = __builtin_amdgcn_mfma_f32_16x16x32_bf16(            \
              bL[n][ks], aB[m][ks], acc[MQ + m][n], 0, 0, 0);                  \
    __builtin_amdgcn_s_setprio(0);                                             \
    if (rd1) {                                                                 \
      _Pragma("unroll") for (int n = 0; n < 2; ++n)                            \
        _Pragma("unroll") for (int ks = 0; ks < 2; ++ks)                       \
          bL[n][ks] = frag(sbN, wc * 64 + n * 16 + r16, ks * 32 + hk * 8);     \
    }                                                                          \
    __builtin_amdgcn_s_barrier();                                              \
  }

  for (int it = 0; it < nt / 2; ++it) {
    const int e = 2 * it;
    TILE_BODY(e,     &sA[0][0], &sB[0][0], &sA[1][0], &sB[1][0]);
    TILE_BODY(e + 1, &sA[1][0], &sB[1][0], &sA[0][0], &sB[0][0]);
  }
#undef TILE_BODY

  // ---- epilogue ----
  bf16* Cp = C;
  const float* bp = bias;
  int ldc = N, colb = col0;
  if constexpr (SPLIT3) {
    int grp = col0 >> 10;
    Cp = grp == 0 ? C : (grp == 1 ? C2 : C3);
    bp = grp == 0 ? bias : (grp == 1 ? bias2 : bias3);
    ldc = 1024;
    colb = col0 & 1023;
  }
#pragma unroll
  for (int m = 0; m < MH; ++m) {
    int row = row0 + wr * (BM_ / 2) + m * 16 + r16;
#pragma unroll
    for (int n = 0; n < 4; ++n) {
      int col = colb + wc * 64 + n * 16 + hk * 4;
      f32x4 b4 = *(const f32x4*)&bp[col];
      f32x4 v;
#pragma unroll
      for (int r = 0; r < 4; ++r) v[r] = acc[m][n][r] + b4[r];
      if (RES == 1) {
        f32x4 rr = *(const f32x4*)&resf[(size_t)row * ldc + col];
#pragma unroll
        for (int r = 0; r < 4; ++r) v[r] += rr[r];
      }
      if (RES == 2) {
        bf16x4 rb = *(const bf16x4*)&resb[(size_t)row * ldc + col];
#pragma unroll
        for (int r = 0; r < 4; ++r) v[r] += (float)rb[r];
      }
      bf16x4 o;
#pragma unroll
      for (int r = 0; r < 4; ++r) {
        float x = v[r];
        if (GELU) x = gelu_fast(x);
        o[r] = (bf16)x;
      }
      *(bf16x4*)&Cp[(size_t)row * ldc + col] = o;
    }
  }
}

// ---------------------------------------------------------------- attention
// one block per (b,h); L=64, dh=64. ctx may alias q.
__global__ __launch_bounds__(256) void attn_k(
    const bf16* q, const bf16* __restrict__ k,
    const bf16* __restrict__ v, const float* __restrict__ rel,
    bf16* ctx) {
  __shared__ alignas(16) bf16 lQ[64 * 64];
  __shared__ alignas(16) bf16 lK[64 * 64];
  __shared__ alignas(16) bf16 lVt[64 * 64];
  __shared__ alignas(16) bf16 lP[4][16 * 64];
  __shared__ float lrel[128];

  const int bh = blockIdx.x;
  const int b = bh >> 4, h = bh & 15;
  const int tid = threadIdx.x;
  const size_t base = (size_t)(b * 64) * DMODEL + h * 64;

#pragma unroll
  for (int i = 0; i < 2; ++i) {
    int j = (tid >> 3) + i * 32;
    int d0 = (tid & 7) * 8;
    *(bf16x8*)&lQ[j * 64 + d0] = *(const bf16x8*)(q + base + (size_t)j * DMODEL + d0);
    *(bf16x8*)&lK[j * 64 + d0] = *(const bf16x8*)(k + base + (size_t)j * DMODEL + d0);
    bf16x8 vvv = *(const bf16x8*)(v + base + (size_t)j * DMODEL + d0);
#pragma unroll
    for (int u = 0; u < 8; ++u) lVt[(d0 + u) * 64 + j] = vvv[u];
  }
  if (tid < 127) lrel[tid] = rel[h * 127 + tid];
  __syncthreads();

  const int lane = tid & 63, w = tid >> 6;
  const int r16 = lane & 15, hk = lane >> 4;

  f32x4 s[4] = {};
#pragma unroll
  for (int dstep = 0; dstep < 2; ++dstep) {
    bf16x8 aq = *(const bf16x8*)&lQ[(w * 16 + r16) * 64 + dstep * 32 + hk * 8];
#pragma unroll
    for (int n = 0; n < 4; ++n) {
      bf16x8 bk_ = *(const bf16x8*)&lK[(n * 16 + r16) * 64 + dstep * 32 + hk * 8];
      s[n] = __builtin_amdgcn_mfma_f32_16x16x32_bf16(aq, bk_, s[n], 0, 0, 0);
    }
  }

  float p[16];
#pragma unroll
  for (int n = 0; n < 4; ++n)
#pragma unroll
    for (int r = 0; r < 4; ++r) {
      int i = w * 16 + hk * 4 + r;
      int j = n * 16 + r16;
      p[n * 4 + r] = s[n][r] * 0.125f + lrel[i - j + 63];
    }
#pragma unroll
  for (int r = 0; r < 4; ++r) {
    float m = fmaxf(fmaxf(p[r], p[4 + r]), fmaxf(p[8 + r], p[12 + r]));
#pragma unroll
    for (int off = 1; off < 16; off <<= 1) m = fmaxf(m, __shfl_xor(m, off));
    float sum = 0.f;
#pragma unroll
    for (int n = 0; n < 4; ++n) {
      p[n * 4 + r] = __expf(p[n * 4 + r] - m);
      sum += p[n * 4 + r];
    }
#pragma unroll
    for (int off = 1; off < 16; off <<= 1) sum += __shfl_xor(sum, off);
    float inv = 1.0f / sum;
#pragma unroll
    for (int n = 0; n < 4; ++n) p[n * 4 + r] *= inv;
  }
#pragma unroll
  for (int n = 0; n < 4; ++n)
#pragma unroll
    for (int r = 0; r < 4; ++r)
      lP[w][(hk * 4 + r) * 64 + n * 16 + r16] = (bf16)p[n * 4 + r];
  __syncthreads();

  f32x4 o[4] = {};
#pragma unroll
  for (int ks = 0; ks < 2; ++ks) {
    bf16x8 ap = *(const bf16x8*)&lP[w][r16 * 64 + ks * 32 + hk * 8];
#pragma unroll
    for (int n = 0; n < 4; ++n) {
      bf16x8 bv_ = *(const bf16x8*)&lVt[(n * 16 + r16) * 64 + ks * 32 + hk * 8];
      o[n] = __builtin_amdgcn_mfma_f32_16x16x32_bf16(ap, bv_, o[n], 0, 0, 0);
    }
  }
#pragma unroll
  for (int n = 0; n < 4; ++n)
#pragma unroll
    for (int r = 0; r < 4; ++r) {
      int trow = b * 64 + w * 16 + hk * 4 + r;
      ctx[(size_t)trow * DMODEL + h * 64 + n * 16 + r16] = (bf16)o[n][r];
    }
}

// ---------------------------------------------------------------- layernorm
template <int F32OUT>
__global__ __launch_bounds__(256) void layernorm_k(
    const bf16* __restrict__ x, const float* __restrict__ g,
    const float* __restrict__ be, bf16* __restrict__ ob,
    float* __restrict__ of) {
  int row = blockIdx.x * 4 + (threadIdx.x >> 6);
  int lane = threadIdx.x & 63;
  const bf16* xr = x + (size_t)row * DMODEL + lane * 16;
  bf16x8 v0 = *(const bf16x8*)xr;
  bf16x8 v1 = *(const bf16x8*)(xr + 8);
  float f[16];
#pragma unroll
  for (int j = 0; j < 8; ++j) { f[j] = (float)v0[j]; f[8 + j] = (float)v1[j]; }
  float s = 0.f, sq = 0.f;
#pragma unroll
  for (int j = 0; j < 16; ++j) { s += f[j]; sq += f[j] * f[j]; }
#pragma unroll
  for (int off = 1; off < 64; off <<= 1) {
    s += __shfl_xor(s, off);
    sq += __shfl_xor(sq, off);
  }
  float mean = s * (1.0f / DMODEL);
  float var = sq * (1.0f / DMODEL) - mean * mean;
  float rstd = rsqrtf(var + 1e-5f);
  const float* gp = g + lane * 16;
  const float* bp = be + lane * 16;
  if (F32OUT) {
    float* op = of + (size_t)row * DMODEL + lane * 16;
#pragma unroll
    for (int j = 0; j < 16; ++j)
      op[j] = (f[j] - mean) * rstd * gp[j] + bp[j];
  } else {
    bf16x8 o0, o1;
#pragma unroll
    for (int j = 0; j < 8; ++j) {
      o0[j] = (bf16)((f[j] - mean) * rstd * gp[j] + bp[j]);
      o1[j] = (bf16)((f[8 + j] - mean) * rstd * gp[8 + j] + bp[8 + j]);
    }
    bf16* op = ob + (size_t)row * DMODEL + lane * 16;
    *(bf16x8*)op = o0;
    *(bf16x8*)(op + 8) = o1;
  }
}

// ---------------------------------------------------------------- launch
extern "C" void kernel_launch(void* const* d_in, const int* in_sizes, int n_in,
                              void* d_out, int out_size, void* d_ws, size_t ws_size,
                              hipStream_t stream) {
  (void)in_sizes; (void)n_in; (void)out_size;
  const float* src = (const float*)d_in[0];
  const float* Wq  = (const float*)d_in[1];
  const float* bq  = (const float*)d_in[2];
  const float* Wk  = (const float*)d_in[3];
  const float* bk  = (const float*)d_in[4];
  const float* Wv  = (const float*)d_in[5];
  const float* bv  = (const float*)d_in[6];
  const float* Wo  = (const float*)d_in[7];
  const float* bo  = (const float*)d_in[8];
  const float* rel = (const float*)d_in[9];
  const float* W1  = (const float*)d_in[10];
  const float* b1  = (const float*)d_in[11];
  const float* W2  = (const float*)d_in[12];
  const float* b2  = (const float*)d_in[13];
  const float* g1  = (const float*)d_in[14];
  const float* be1 = (const float*)d_in[15];
  const float* g2  = (const float*)d_in[16];
  const float* be2 = (const float*)d_in[17];

  // ws plan: REGION0 = ws[0:64MiB] (srcb+qb -> hbuf -> lnout);
  // weights ws[64:88MiB] (WqT/WkT/WvT contiguous => fused QKV B matrix);
  // y2 in ws[88:120MiB] when ws_size allows, else d_out + copy-out.
  char* ws = (char*)d_ws;
  const size_t MiB = 1ull << 20;
  bf16* srcb = (bf16*)(ws + 0 * MiB);
  bf16* qb   = (bf16*)(ws + 32 * MiB);
  bf16* WqT  = (bf16*)(ws + 64 * MiB);   // [3072][1024] fused: Wq|Wk|Wv
  bf16* WkT  = (bf16*)(ws + 66 * MiB);
  bf16* WvT  = (bf16*)(ws + 68 * MiB);
  bf16* WoT  = (bf16*)(ws + 70 * MiB);
  bf16* W1T  = (bf16*)(ws + 72 * MiB);
  bf16* W2T  = (bf16*)(ws + 80 * MiB);
  bf16* hbuf = (bf16*)(ws + 0 * MiB);
  float* lnout = (float*)(ws + 0 * MiB);
  bf16* kb = (bf16*)d_out;
  bf16* vb = (bf16*)((char*)d_out + 32 * MiB);
  bf16* y1 = kb;
  bf16* xb = vb;
  const bool bigws = (ws_size >= 121 * MiB);
  bf16* y2 = bigws ? (bf16*)(ws + 88 * MiB) : kb;

  cvt_copy<<<(N_TOK * DMODEL) / 2048, 256, 0, stream>>>(src, srcb);
  dim3 tb(32, 8);
  convt<<<dim3(32, 32), tb, 0, stream>>>(Wq, WqT, 1024, 1024);
  convt<<<dim3(32, 32), tb, 0, stream>>>(Wk, WkT, 1024, 1024);
  convt<<<dim3(32, 32), tb, 0, stream>>>(Wv, WvT, 1024, 1024);
  convt<<<dim3(32, 32), tb, 0, stream>>>(Wo, WoT, 1024, 1024);
  convt<<<dim3(128, 32), tb, 0, stream>>>(W1, W1T, 1024, 4096);
  convt<<<dim3(32, 128), tb, 0, stream>>>(W2, W2T, 4096, 1024);

  // fused QKV: one GEMM, N=3072 (WqT/WkT/WvT contiguous), split outputs
  const int gQKV3 = (N_TOK / 256) * (3072 / 256);   // 64*12 = 768
  gemm_c<256, 0, 0, 1><<<gQKV3, 512, 0, stream>>>(
      srcb, WqT, bq, bk, bv, nullptr, nullptr, qb, kb, vb, N_TOK, 3072, DMODEL);

  attn_k<<<256 * NHEAD, 256, 0, stream>>>(qb, kb, vb, rel, qb);

  const int gD = (N_TOK / 256) * (DMODEL / 256);    // 256
  // y1 = ctx @ Wo + bo + src (fp32 residual) -> DO0
  gemm_c<256, 1, 0, 0><<<gD, 512, 0, stream>>>(
      qb, WoT, bo, nullptr, nullptr, src, nullptr, y1, nullptr, nullptr, N_TOK, DMODEL, DMODEL);
  // x = LN1(y1) -> DO1
  layernorm_k<0><<<N_TOK / 4, 256, 0, stream>>>(y1, g1, be1, xb, nullptr);

  // FFN in 2 chunks of 8192 rows; h (8192x4096 bf16 = 64 MiB) in REGION0
  const int CH = 8192;
  const int gF1 = (CH / 256) * (FDIM / 256);     // 32*16 = 512
  const int gF2 = (CH / 128) * (DMODEL / 256);   // 64*4  = 256  (BM=128)
  for (int c = 0; c < 2; ++c) {
    const bf16* xc = xb + (size_t)c * CH * DMODEL;
    bf16* yc = y2 + (size_t)c * CH * DMODEL;
    gemm_c<256, 0, 1, 0><<<gF1, 512, 0, stream>>>(
        xc, W1T, b1, nullptr, nullptr, nullptr, nullptr, hbuf, nullptr, nullptr, CH, FDIM, DMODEL);
    gemm_c<128, 2, 0, 0><<<gF2, 512, 0, stream>>>(
        hbuf, W2T, b2, nullptr, nullptr, nullptr, xc, yc, nullptr, nullptr, CH, DMODEL, FDIM);
  }
  if (bigws) {
    layernorm_k<1><<<N_TOK / 4, 256, 0, stream>>>(y2, g2, be2, nullptr, (float*)d_out);
  } else {
    layernorm_k<1><<<N_TOK / 4, 256, 0, stream>>>(y2, g2, be2, nullptr, lnout);
    hipMemcpyAsync(d_out, lnout, (size_t)N_TOK * DMODEL * 4, hipMemcpyDeviceToDevice, stream);
  }
}

// Round 10
// 660.687 us; speedup vs baseline: 1.4812x; 1.0025x over previous
//
#include <hip/hip_runtime.h>

typedef __bf16 bf16;
typedef __attribute__((ext_vector_type(8))) __bf16 bf16x8;
typedef __attribute__((ext_vector_type(4))) __bf16 bf16x4;
typedef __attribute__((ext_vector_type(4))) float f32x4;
typedef __attribute__((ext_vector_type(16))) float f32x16;

#define N_TOK 16384
#define DMODEL 1024
#define FDIM 4096
#define NHEAD 16

// ---------------------------------------------------------------- helpers
__device__ __forceinline__ void gload_lds16(const bf16* g, bf16* l) {
  __builtin_amdgcn_global_load_lds(
      (const __attribute__((address_space(1))) void*)g,
      (__attribute__((address_space(3))) void*)l,
      16, 0, 0);
}

// gelu(x) = 0.5x(1+tanh(z)) = x / (1 + exp(-2z)),  z = 0.79788456(x + 0.044715x^3)
__device__ __forceinline__ float gelu_fast(float x) {
  float z2 = 1.5957691216057308f * (x + 0.044715f * x * x * x);
  return x / (1.0f + __expf(-z2));
}

// ---------------------------------------------------------------- fp32 -> bf16 copy
__global__ __launch_bounds__(256) void cvt_copy(const float* __restrict__ x,
                                                bf16* __restrict__ y) {
  size_t i = ((size_t)blockIdx.x * 256 + threadIdx.x) * 8;
  float4 a = *(const float4*)(x + i);
  float4 b = *(const float4*)(x + i + 4);
  bf16x8 o;
  o[0] = (bf16)a.x; o[1] = (bf16)a.y; o[2] = (bf16)a.z; o[3] = (bf16)a.w;
  o[4] = (bf16)b.x; o[5] = (bf16)b.y; o[6] = (bf16)b.z; o[7] = (bf16)b.w;
  *(bf16x8*)(y + i) = o;
}

// ---------------------------------------------------------------- convert+transpose
__global__ void convt(const float* __restrict__ src, bf16* __restrict__ dst,
                      int R, int C) {
  __shared__ float tile[32][33];
  int c0 = blockIdx.x * 32, r0 = blockIdx.y * 32;
  int tx = threadIdx.x, ty = threadIdx.y;
#pragma unroll
  for (int i = 0; i < 4; ++i)
    tile[ty * 4 + i][tx] = src[(size_t)(r0 + ty * 4 + i) * C + c0 + tx];
  __syncthreads();
#pragma unroll
  for (int i = 0; i < 4; ++i)
    dst[(size_t)(c0 + ty * 4 + i) * R + r0 + tx] = (bf16)tile[tx][ty * 4 + i];
}

// ---------------------------------------------------------------- counted-vmcnt GEMM (32x32x16 MFMA)
// C[M][N] = A[M][K] @ BT[N][K]^T + bias (+res) (+gelu); output bf16.
// BM_ in {256,128}, BN=256, BK=64. 512 threads, 8 waves (2Mx4N).
// R7's proven schedule: 2 LDS buffers; 4 phases/K-tile; 0-conflict XOR
// swizzle (chunk^=row&7); stage B(t+2)@P2, A(t+2)@P3 into buf t&1; single
// counted vmcnt(8|6) per tile at P3 leaves t+2's loads in flight (T4).
// MFMA switched 16x16x32 -> 32x32x16 (swapped operands): 32 MFMA/tile/wave
// at ~8.07cyc vs 64 at ~4.85 (-17% matrix-pipe); same ds_read count/bytes.
// D = mfma(bF, aF): lane holds output row = lane&31 (fixed), 16 regs =
// cols (reg&3) + 8*(reg>>2) + 4*(lane>>5)  [m74/m101-verified C/D layout].
// A/B frag: row = lane&31, k = (lane>>5)*8 + j (doubled-K family layout).
template <int BM_, int RES, int GELU, int SPLIT3>  // RES: 0 none, 1 fp32, 2 bf16
__global__ __launch_bounds__(512) void gemm_c(
    const bf16* __restrict__ A, const bf16* __restrict__ BT,
    const float* __restrict__ bias, const float* __restrict__ bias2,
    const float* __restrict__ bias3, const float* __restrict__ resf,
    const bf16* __restrict__ resb, bf16* __restrict__ C,
    bf16* __restrict__ C2, bf16* __restrict__ C3,
    int M, int N, int K) {
  constexpr int ALOADS = BM_ / 64;     // gloads/thread per A tile (4 or 2)
  constexpr int MT = BM_ / 64;         // 32-row m-tiles per wave (4 or 2)
  constexpr int MQ = MT / 2;           // m-tiles per quadrant (2 or 1)
  __shared__ alignas(16) bf16 sA[2][BM_ * 64];
  __shared__ alignas(16) bf16 sB[2][256 * 64];

  const int tid = threadIdx.x;
  const int lane = tid & 63, wv = tid >> 6;
  const int wr = wv >> 2, wc = wv & 3;       // 2 x 4 wave grid
  const int l31 = lane & 31, hi5 = lane >> 5;

  const int nbn = N >> 8;
  const int cpx = gridDim.x >> 3;            // grid % 8 == 0
  const int swz = ((int)blockIdx.x & 7) * cpx + ((int)blockIdx.x >> 3);
  const int row0 = (swz / nbn) * BM_, col0 = (swz % nbn) << 8;

  const bf16* Ab = A + (size_t)row0 * K;
  const bf16* Bb = BT + (size_t)col0 * K;

  // hoisted per-thread staging source bases (inverse-swizzled source col)
  const bf16* gA[ALOADS];
  const bf16* gB[4];
#pragma unroll
  for (int l = 0; l < ALOADS; ++l) {
    int g = l * 512 + tid, r = g >> 3, p = g & 7;
    gA[l] = Ab + (size_t)r * K + ((p ^ (r & 7)) << 3);
  }
#pragma unroll
  for (int l = 0; l < 4; ++l) {
    int g = l * 512 + tid, r = g >> 3, p = g & 7;
    gB[l] = Bb + (size_t)r * K + ((p ^ (r & 7)) << 3);
  }

  auto stageA = [&](int buf, int kt) {
    const size_t ko = (size_t)kt << 6;
#pragma unroll
    for (int l = 0; l < ALOADS; ++l)
      gload_lds16(gA[l] + ko, &sA[buf][(l * 512 + tid) * 8]);
  };
  auto stageB = [&](int buf, int kt) {
    const size_t ko = (size_t)kt << 6;
#pragma unroll
    for (int l = 0; l < 4; ++l)
      gload_lds16(gB[l] + ko, &sB[buf][(l * 512 + tid) * 8]);
  };
  auto frag = [&](const bf16* s, int row, int kc) -> bf16x8 {
    return *(const bf16x8*)(s + row * 64 + (kc ^ ((row & 7) * 8)));
  };

  f32x16 acc[MT][2] = {};
  bf16x8 aF[MQ][4], bF0[4], bF1[4];

  const int nt = K >> 6;
  // prologue: stage tiles 0,1; drain tile 0, leave tile 1 in flight
  stageA(0, 0); stageB(0, 0);
  stageA(1, 1); stageB(1, 1);
  if constexpr (BM_ == 256) asm volatile("s_waitcnt vmcnt(8)" ::: "memory");
  else                      asm volatile("s_waitcnt vmcnt(6)" ::: "memory");
  __builtin_amdgcn_s_barrier();

  for (int kt = 0; kt < nt; ++kt) {
    const int cb = kt & 1;
    const bf16* sa = &sA[cb][0];
    const bf16* sb = &sB[cb][0];
    const bool pf = (kt + 2 < nt);

    // ---- P0: read aF(m-lo) + bF0(nt0); MFMA (m-lo, nt0) ----
#pragma unroll
    for (int mq = 0; mq < MQ; ++mq)
#pragma unroll
      for (int kk = 0; kk < 4; ++kk)
        aF[mq][kk] = frag(sa, wr * (BM_ / 2) + mq * 32 + l31, kk * 16 + hi5 * 8);
#pragma unroll
    for (int kk = 0; kk < 4; ++kk)
      bF0[kk] = frag(sb, wc * 64 + l31, kk * 16 + hi5 * 8);
    __builtin_amdgcn_s_barrier();
    __builtin_amdgcn_s_setprio(1);
#pragma unroll
    for (int kk = 0; kk < 4; ++kk)
#pragma unroll
      for (int mq = 0; mq < MQ; ++mq)
        acc[mq][0] = __builtin_amdgcn_mfma_f32_32x32x16_bf16(bF0[kk], aF[mq][kk], acc[mq][0], 0, 0, 0);
    __builtin_amdgcn_s_setprio(0);
    __builtin_amdgcn_s_barrier();

    // ---- P1: read bF1(nt1); MFMA (m-lo, nt1) ----
#pragma unroll
    for (int kk = 0; kk < 4; ++kk)
      bF1[kk] = frag(sb, wc * 64 + 32 + l31, kk * 16 + hi5 * 8);
    __builtin_amdgcn_s_barrier();
    __builtin_amdgcn_s_setprio(1);
#pragma unroll
    for (int kk = 0; kk < 4; ++kk)
#pragma unroll
      for (int mq = 0; mq < MQ; ++mq)
        acc[mq][1] = __builtin_amdgcn_mfma_f32_32x32x16_bf16(bF1[kk], aF[mq][kk], acc[mq][1], 0, 0, 0);
    __builtin_amdgcn_s_setprio(0);
    __builtin_amdgcn_s_barrier();

    // ---- P2: read aF(m-hi); stage B(t+2); MFMA (m-hi, nt1) ----
#pragma unroll
    for (int mq = 0; mq < MQ; ++mq)
#pragma unroll
      for (int kk = 0; kk < 4; ++kk)
        aF[mq][kk] = frag(sa, wr * (BM_ / 2) + (MQ + mq) * 32 + l31, kk * 16 + hi5 * 8);
    if (pf) stageB(cb, kt + 2);
    __builtin_amdgcn_s_barrier();
    __builtin_amdgcn_s_setprio(1);
#pragma unroll
    for (int kk = 0; kk < 4; ++kk)
#pragma unroll
      for (int mq = 0; mq < MQ; ++mq)
        acc[MQ + mq][1] = __builtin_amdgcn_mfma_f32_32x32x16_bf16(bF1[kk], aF[mq][kk], acc[MQ + mq][1], 0, 0, 0);
    __builtin_amdgcn_s_setprio(0);
    __builtin_amdgcn_s_barrier();

    // ---- P3: stage A(t+2); MFMA (m-hi, nt0); counted wait ----
    if (pf) stageA(cb, kt + 2);
    __builtin_amdgcn_s_setprio(1);
#pragma unroll
    for (int kk = 0; kk < 4; ++kk)
#pragma unroll
      for (int mq = 0; mq < MQ; ++mq)
        acc[MQ + mq][0] = __builtin_amdgcn_mfma_f32_32x32x16_bf16(bF0[kk], aF[mq][kk], acc[MQ + mq][0], 0, 0, 0);
    __builtin_amdgcn_s_setprio(0);
    if (pf) {
      // completes tile t+1 (issued last tile); leaves t+2 in flight
      if constexpr (BM_ == 256) asm volatile("s_waitcnt vmcnt(8)" ::: "memory");
      else                      asm volatile("s_waitcnt vmcnt(6)" ::: "memory");
    } else if (kt + 1 < nt) {
      asm volatile("s_waitcnt vmcnt(0)" ::: "memory");
    }
    __builtin_amdgcn_s_barrier();
  }

  // ---- epilogue: lane holds row = ..+mt*32+l31; cols g*8 + hi5*4 + 0..3 ----
  bf16* Cp = C;
  const float* bp = bias;
  int ldc = N, colb = col0;
  if constexpr (SPLIT3) {
    int grp = col0 >> 10;
    Cp = grp == 0 ? C : (grp == 1 ? C2 : C3);
    bp = grp == 0 ? bias : (grp == 1 ? bias2 : bias3);
    ldc = 1024;
    colb = col0 & 1023;
  }
#pragma unroll
  for (int mt = 0; mt < MT; ++mt) {
    int row = row0 + wr * (BM_ / 2) + mt * 32 + l31;
#pragma unroll
    for (int ntl = 0; ntl < 2; ++ntl) {
#pragma unroll
      for (int g = 0; g < 4; ++g) {
        int col = colb + wc * 64 + ntl * 32 + g * 8 + hi5 * 4;
        f32x4 b4 = *(const f32x4*)&bp[col];
        f32x4 v;
#pragma unroll
        for (int r = 0; r < 4; ++r) v[r] = acc[mt][ntl][g * 4 + r] + b4[r];
        if (RES == 1) {
          f32x4 rr = *(const f32x4*)&resf[(size_t)row * ldc + col];
#pragma unroll
          for (int r = 0; r < 4; ++r) v[r] += rr[r];
        }
        if (RES == 2) {
          bf16x4 rb = *(const bf16x4*)&resb[(size_t)row * ldc + col];
#pragma unroll
          for (int r = 0; r < 4; ++r) v[r] += (float)rb[r];
        }
        bf16x4 o;
#pragma unroll
        for (int r = 0; r < 4; ++r) {
          float x = v[r];
          if (GELU) x = gelu_fast(x);
          o[r] = (bf16)x;
        }
        *(bf16x4*)&Cp[(size_t)row * ldc + col] = o;
      }
    }
  }
}

// ---------------------------------------------------------------- attention
// one block per (b,h); L=64, dh=64. ctx may alias q.
__global__ __launch_bounds__(256) void attn_k(
    const bf16* q, const bf16* __restrict__ k,
    const bf16* __restrict__ v, const float* __restrict__ rel,
    bf16* ctx) {
  __shared__ alignas(16) bf16 lQ[64 * 64];
  __shared__ alignas(16) bf16 lK[64 * 64];
  __shared__ alignas(16) bf16 lVt[64 * 64];
  __shared__ alignas(16) bf16 lP[4][16 * 64];
  __shared__ float lrel[128];

  const int bh = blockIdx.x;
  const int b = bh >> 4, h = bh & 15;
  const int tid = threadIdx.x;
  const size_t base = (size_t)(b * 64) * DMODEL + h * 64;

#pragma unroll
  for (int i = 0; i < 2; ++i) {
    int j = (tid >> 3) + i * 32;
    int d0 = (tid & 7) * 8;
    *(bf16x8*)&lQ[j * 64 + d0] = *(const bf16x8*)(q + base + (size_t)j * DMODEL + d0);
    *(bf16x8*)&lK[j * 64 + d0] = *(const bf16x8*)(k + base + (size_t)j * DMODEL + d0);
    bf16x8 vvv = *(const bf16x8*)(v + base + (size_t)j * DMODEL + d0);
#pragma unroll
    for (int u = 0; u < 8; ++u) lVt[(d0 + u) * 64 + j] = vvv[u];
  }
  if (tid < 127) lrel[tid] = rel[h * 127 + tid];
  __syncthreads();

  const int lane = tid & 63, w = tid >> 6;
  const int r16 = lane & 15, hk = lane >> 4;

  f32x4 s[4] = {};
#pragma unroll
  for (int dstep = 0; dstep < 2; ++dstep) {
    bf16x8 aq = *(const bf16x8*)&lQ[(w * 16 + r16) * 64 + dstep * 32 + hk * 8];
#pragma unroll
    for (int n = 0; n < 4; ++n) {
      bf16x8 bk_ = *(const bf16x8*)&lK[(n * 16 + r16) * 64 + dstep * 32 + hk * 8];
      s[n] = __builtin_amdgcn_mfma_f32_16x16x32_bf16(aq, bk_, s[n], 0, 0, 0);
    }
  }

  float p[16];
#pragma unroll
  for (int n = 0; n < 4; ++n)
#pragma unroll
    for (int r = 0; r < 4; ++r) {
      int i = w * 16 + hk * 4 + r;
      int j = n * 16 + r16;
      p[n * 4 + r] = s[n][r] * 0.125f + lrel[i - j + 63];
    }
#pragma unroll
  for (int r = 0; r < 4; ++r) {
    float m = fmaxf(fmaxf(p[r], p[4 + r]), fmaxf(p[8 + r], p[12 + r]));
#pragma unroll
    for (int off = 1; off < 16; off <<= 1) m = fmaxf(m, __shfl_xor(m, off));
    float sum = 0.f;
#pragma unroll
    for (int n = 0; n < 4; ++n) {
      p[n * 4 + r] = __expf(p[n * 4 + r] - m);
      sum += p[n * 4 + r];
    }
#pragma unroll
    for (int off = 1; off < 16; off <<= 1) sum += __shfl_xor(sum, off);
    float inv = 1.0f / sum;
#pragma unroll
    for (int n = 0; n < 4; ++n) p[n * 4 + r] *= inv;
  }
#pragma unroll
  for (int n = 0; n < 4; ++n)
#pragma unroll
    for (int r = 0; r < 4; ++r)
      lP[w][(hk * 4 + r) * 64 + n * 16 + r16] = (bf16)p[n * 4 + r];
  __syncthreads();

  f32x4 o[4] = {};
#pragma unroll
  for (int ks = 0; ks < 2; ++ks) {
    bf16x8 ap = *(const bf16x8*)&lP[w][r16 * 64 + ks * 32 + hk * 8];
#pragma unroll
    for (int n = 0; n < 4; ++n) {
      bf16x8 bv_ = *(const bf16x8*)&lVt[(n * 16 + r16) * 64 + ks * 32 + hk * 8];
      o[n] = __builtin_amdgcn_mfma_f32_16x16x32_bf16(ap, bv_, o[n], 0, 0, 0);
    }
  }
#pragma unroll
  for (int n = 0; n < 4; ++n)
#pragma unroll
    for (int r = 0; r < 4; ++r) {
      int trow = b * 64 + w * 16 + hk * 4 + r;
      ctx[(size_t)trow * DMODEL + h * 64 + n * 16 + r16] = (bf16)o[n][r];
    }
}

// ---------------------------------------------------------------- layernorm
template <int F32OUT>
__global__ __launch_bounds__(256) void layernorm_k(
    const bf16* __restrict__ x, const float* __restrict__ g,
    const float* __restrict__ be, bf16* __restrict__ ob,
    float* __restrict__ of) {
  int row = blockIdx.x * 4 + (threadIdx.x >> 6);
  int lane = threadIdx.x & 63;
  const bf16* xr = x + (size_t)row * DMODEL + lane * 16;
  bf16x8 v0 = *(const bf16x8*)xr;
  bf16x8 v1 = *(const bf16x8*)(xr + 8);
  float f[16];
#pragma unroll
  for (int j = 0; j < 8; ++j) { f[j] = (float)v0[j]; f[8 + j] = (float)v1[j]; }
  float s = 0.f, sq = 0.f;
#pragma unroll
  for (int j = 0; j < 16; ++j) { s += f[j]; sq += f[j] * f[j]; }
#pragma unroll
  for (int off = 1; off < 64; off <<= 1) {
    s += __shfl_xor(s, off);
    sq += __shfl_xor(sq, off);
  }
  float mean = s * (1.0f / DMODEL);
  float var = sq * (1.0f / DMODEL) - mean * mean;
  float rstd = rsqrtf(var + 1e-5f);
  const float* gp = g + lane * 16;
  const float* bp = be + lane * 16;
  if (F32OUT) {
    float* op = of + (size_t)row * DMODEL + lane * 16;
#pragma unroll
    for (int j = 0; j < 16; ++j)
      op[j] = (f[j] - mean) * rstd * gp[j] + bp[j];
  } else {
    bf16x8 o0, o1;
#pragma unroll
    for (int j = 0; j < 8; ++j) {
      o0[j] = (bf16)((f[j] - mean) * rstd * gp[j] + bp[j]);
      o1[j] = (bf16)((f[8 + j] - mean) * rstd * gp[8 + j] + bp[8 + j]);
    }
    bf16* op = ob + (size_t)row * DMODEL + lane * 16;
    *(bf16x8*)op = o0;
    *(bf16x8*)(op + 8) = o1;
  }
}

// ---------------------------------------------------------------- launch
extern "C" void kernel_launch(void* const* d_in, const int* in_sizes, int n_in,
                              void* d_out, int out_size, void* d_ws, size_t ws_size,
                              hipStream_t stream) {
  (void)in_sizes; (void)n_in; (void)out_size;
  const float* src = (const float*)d_in[0];
  const float* Wq  = (const float*)d_in[1];
  const float* bq  = (const float*)d_in[2];
  const float* Wk  = (const float*)d_in[3];
  const float* bk  = (const float*)d_in[4];
  const float* Wv  = (const float*)d_in[5];
  const float* bv  = (const float*)d_in[6];
  const float* Wo  = (const float*)d_in[7];
  const float* bo  = (const float*)d_in[8];
  const float* rel = (const float*)d_in[9];
  const float* W1  = (const float*)d_in[10];
  const float* b1  = (const float*)d_in[11];
  const float* W2  = (const float*)d_in[12];
  const float* b2  = (const float*)d_in[13];
  const float* g1  = (const float*)d_in[14];
  const float* be1 = (const float*)d_in[15];
  const float* g2  = (const float*)d_in[16];
  const float* be2 = (const float*)d_in[17];

  // ws plan: REGION0 = ws[0:64MiB] (srcb+qb -> hbuf -> lnout);
  // weights ws[64:88MiB] (WqT/WkT/WvT contiguous => fused QKV B matrix);
  // y2 in ws[88:120MiB] when ws_size allows, else d_out + copy-out.
  char* ws = (char*)d_ws;
  const size_t MiB = 1ull << 20;
  bf16* srcb = (bf16*)(ws + 0 * MiB);
  bf16* qb   = (bf16*)(ws + 32 * MiB);
  bf16* WqT  = (bf16*)(ws + 64 * MiB);   // [3072][1024] fused: Wq|Wk|Wv
  bf16* WkT  = (bf16*)(ws + 66 * MiB);
  bf16* WvT  = (bf16*)(ws + 68 * MiB);
  bf16* WoT  = (bf16*)(ws + 70 * MiB);
  bf16* W1T  = (bf16*)(ws + 72 * MiB);
  bf16* W2T  = (bf16*)(ws + 80 * MiB);
  bf16* hbuf = (bf16*)(ws + 0 * MiB);
  float* lnout = (float*)(ws + 0 * MiB);
  bf16* kb = (bf16*)d_out;
  bf16* vb = (bf16*)((char*)d_out + 32 * MiB);
  bf16* y1 = kb;
  bf16* xb = vb;
  const bool bigws = (ws_size >= 121 * MiB);
  bf16* y2 = bigws ? (bf16*)(ws + 88 * MiB) : kb;

  cvt_copy<<<(N_TOK * DMODEL) / 2048, 256, 0, stream>>>(src, srcb);
  dim3 tb(32, 8);
  convt<<<dim3(32, 32), tb, 0, stream>>>(Wq, WqT, 1024, 1024);
  convt<<<dim3(32, 32), tb, 0, stream>>>(Wk, WkT, 1024, 1024);
  convt<<<dim3(32, 32), tb, 0, stream>>>(Wv, WvT, 1024, 1024);
  convt<<<dim3(32, 32), tb, 0, stream>>>(Wo, WoT, 1024, 1024);
  convt<<<dim3(128, 32), tb, 0, stream>>>(W1, W1T, 1024, 4096);
  convt<<<dim3(32, 128), tb, 0, stream>>>(W2, W2T, 4096, 1024);

  // fused QKV: one GEMM, N=3072 (WqT/WkT/WvT contiguous), split outputs
  const int gQKV3 = (N_TOK / 256) * (3072 / 256);   // 64*12 = 768
  gemm_c<256, 0, 0, 1><<<gQKV3, 512, 0, stream>>>(
      srcb, WqT, bq, bk, bv, nullptr, nullptr, qb, kb, vb, N_TOK, 3072, DMODEL);

  attn_k<<<256 * NHEAD, 256, 0, stream>>>(qb, kb, vb, rel, qb);

  const int gD = (N_TOK / 256) * (DMODEL / 256);    // 256
  // y1 = ctx @ Wo + bo + src (fp32 residual) -> DO0
  gemm_c<256, 1, 0, 0><<<gD, 512, 0, stream>>>(
      qb, WoT, bo, nullptr, nullptr, src, nullptr, y1, nullptr, nullptr, N_TOK, DMODEL, DMODEL);
  // x = LN1(y1) -> DO1
  layernorm_k<0><<<N_TOK / 4, 256, 0, stream>>>(y1, g1, be1, xb, nullptr);

  // FFN in 2 chunks of 8192 rows; h (8192x4096 bf16 = 64 MiB) in REGION0
  const int CH = 8192;
  const int gF1 = (CH / 256) * (FDIM / 256);     // 32*16 = 512
  const int gF2 = (CH / 128) * (DMODEL / 256);   // 64*4  = 256  (BM=128)
  for (int c = 0; c < 2; ++c) {
    const bf16* xc = xb + (size_t)c * CH * DMODEL;
    bf16* yc = y2 + (size_t)c * CH * DMODEL;
    gemm_c<256, 0, 1, 0><<<gF1, 512, 0, stream>>>(
        xc, W1T, b1, nullptr, nullptr, nullptr, nullptr, hbuf, nullptr, nullptr, CH, FDIM, DMODEL);
    gemm_c<128, 2, 0, 0><<<gF2, 512, 0, stream>>>(
        hbuf, W2T, b2, nullptr, nullptr, nullptr, xc, yc, nullptr, nullptr, CH, DMODEL, FDIM);
  }
  if (bigws) {
    layernorm_k<1><<<N_TOK / 4, 256, 0, stream>>>(y2, g2, be2, nullptr, (float*)d_out);
  } else {
    layernorm_k<1><<<N_TOK / 4, 256, 0, stream>>>(y2, g2, be2, nullptr, lnout);
    hipMemcpyAsync(d_out, lnout, (size_t)N_TOK * DMODEL * 4, hipMemcpyDeviceToDevice, stream);
  }
}

// Round 11
// 606.967 us; speedup vs baseline: 1.6123x; 1.0885x over previous
//
#include <hip/hip_runtime.h>

typedef __bf16 bf16;
typedef __attribute__((ext_vector_type(8))) __bf16 bf16x8;
typedef __attribute__((ext_vector_type(4))) __bf16 bf16x4;
typedef __attribute__((ext_vector_type(4))) float f32x4;

#define N_TOK 16384
#define DMODEL 1024
#define FDIM 4096
#define NHEAD 16

// ---------------------------------------------------------------- helpers
__device__ __forceinline__ void gload_lds16(const bf16* g, bf16* l) {
  __builtin_amdgcn_global_load_lds(
      (const __attribute__((address_space(1))) void*)g,
      (__attribute__((address_space(3))) void*)l,
      16, 0, 0);
}

// gelu(x) = 0.5x(1+tanh(z)) = x / (1 + exp(-2z)),  z = 0.79788456(x + 0.044715x^3)
__device__ __forceinline__ float gelu_fast(float x) {
  float z2 = 1.5957691216057308f * (x + 0.044715f * x * x * x);
  return x / (1.0f + __expf(-z2));
}

// ---------------------------------------------------------------- fp32 -> bf16 copy
__global__ __launch_bounds__(256) void cvt_copy(const float* __restrict__ x,
                                                bf16* __restrict__ y) {
  size_t i = ((size_t)blockIdx.x * 256 + threadIdx.x) * 8;
  float4 a = *(const float4*)(x + i);
  float4 b = *(const float4*)(x + i + 4);
  bf16x8 o;
  o[0] = (bf16)a.x; o[1] = (bf16)a.y; o[2] = (bf16)a.z; o[3] = (bf16)a.w;
  o[4] = (bf16)b.x; o[5] = (bf16)b.y; o[6] = (bf16)b.z; o[7] = (bf16)b.w;
  *(bf16x8*)(y + i) = o;
}

// ---------------------------------------------------------------- convert+transpose
__global__ void convt(const float* __restrict__ src, bf16* __restrict__ dst,
                      int R, int C) {
  __shared__ float tile[32][33];
  int c0 = blockIdx.x * 32, r0 = blockIdx.y * 32;
  int tx = threadIdx.x, ty = threadIdx.y;
#pragma unroll
  for (int i = 0; i < 4; ++i)
    tile[ty * 4 + i][tx] = src[(size_t)(r0 + ty * 4 + i) * C + c0 + tx];
  __syncthreads();
#pragma unroll
  for (int i = 0; i < 4; ++i)
    dst[(size_t)(c0 + ty * 4 + i) * R + r0 + tx] = (bf16)tile[tx][ty * 4 + i];
}

// ---------------------------------------------------------------- counted-vmcnt GEMM (R7, proven)
// C[M][N] = A[M][K] @ BT[N][K]^T + bias (+res) (+gelu); output bf16.
// BM_ in {256,128}, BN=256, BK=64. 512 threads, 8 waves (2Mx4N).
// 2 LDS buffers; 4 phases/K-tile; 0-conflict XOR swizzle (chunk^=row&7).
// Counted pipeline: P2 stages B(t+2), P3 stages A(t+2) into buffer t&1;
// single vmcnt(8|6) per tile leaves t+2's loads in flight (T4).
template <int BM_, int RES, int GELU, int SPLIT3>  // RES: 0 none, 1 fp32, 2 bf16
__global__ __launch_bounds__(512) void gemm_c(
    const bf16* __restrict__ A, const bf16* __restrict__ BT,
    const float* __restrict__ bias, const float* __restrict__ bias2,
    const float* __restrict__ bias3, const float* __restrict__ resf,
    const bf16* __restrict__ resb, bf16* __restrict__ C,
    bf16* __restrict__ C2, bf16* __restrict__ C3,
    int M, int N, int K) {
  constexpr int ALOADS = BM_ / 64;     // gloads/thread for an A tile (4 or 2)
  constexpr int MH = BM_ / 32;         // m-frags per wave (8 or 4)
  constexpr int MQ = MH / 2;           // m-frags per quadrant (4 or 2)
  __shared__ alignas(16) bf16 sA[2][BM_ * 64];
  __shared__ alignas(16) bf16 sB[2][256 * 64];

  const int tid = threadIdx.x;
  const int lane = tid & 63, wv = tid >> 6;
  const int wr = wv >> 2, wc = wv & 3;       // 2 x 4 wave grid
  const int r16 = lane & 15, hk = lane >> 4;

  const int nbn = N >> 8;
  const int cpx = gridDim.x >> 3;            // grid % 8 == 0
  const int swz = ((int)blockIdx.x & 7) * cpx + ((int)blockIdx.x >> 3);
  const int row0 = (swz / nbn) * BM_, col0 = (swz % nbn) << 8;

  const bf16* Ab = A + (size_t)row0 * K;
  const bf16* Bb = BT + (size_t)col0 * K;

  // hoisted per-thread staging source bases (compile-time indexed -> regs)
  const bf16* gA[ALOADS];
  const bf16* gB[4];
#pragma unroll
  for (int l = 0; l < ALOADS; ++l) {
    int g = l * 512 + tid, r = g >> 3, p = g & 7;
    gA[l] = Ab + (size_t)r * K + ((p ^ (r & 7)) << 3);
  }
#pragma unroll
  for (int l = 0; l < 4; ++l) {
    int g = l * 512 + tid, r = g >> 3, p = g & 7;
    gB[l] = Bb + (size_t)r * K + ((p ^ (r & 7)) << 3);
  }

  auto stageA = [&](int buf, int kt) {
    const size_t ko = (size_t)kt << 6;
#pragma unroll
    for (int l = 0; l < ALOADS; ++l)
      gload_lds16(gA[l] + ko, &sA[buf][(l * 512 + tid) * 8]);
  };
  auto stageB = [&](int buf, int kt) {
    const size_t ko = (size_t)kt << 6;
#pragma unroll
    for (int l = 0; l < 4; ++l)
      gload_lds16(gB[l] + ko, &sB[buf][(l * 512 + tid) * 8]);
  };
  // swizzled fragment read (row local, kc in elements)
  auto frag = [&](const bf16* s, int row, int kc) -> bf16x8 {
    return *(const bf16x8*)(s + row * 64 + (kc ^ ((row & 7) * 8)));
  };

  f32x4 acc[MH][4] = {};
  bf16x8 aF[MQ][2], bF0[2][2], bF1[2][2];

  const int nt = K >> 6;
  // prologue: tiles 0 and 1; wait tile 0 complete, leave tile 1 in flight
  stageA(0, 0); stageB(0, 0);
  stageA(1, 1); stageB(1, 1);
  if constexpr (BM_ == 256) asm volatile("s_waitcnt vmcnt(8)" ::: "memory");
  else                      asm volatile("s_waitcnt vmcnt(6)" ::: "memory");
  __builtin_amdgcn_s_barrier();

  for (int kt = 0; kt < nt; ++kt) {
    const int cb = kt & 1;
    const bf16* sa = &sA[cb][0];
    const bf16* sb = &sB[cb][0];
    const bool pf = (kt + 2 < nt);

    // ---- P0: read a-half0 + b-half0; MFMA Q(m-lo, n0-1) ----
#pragma unroll
    for (int m = 0; m < MQ; ++m)
#pragma unroll
      for (int ks = 0; ks < 2; ++ks)
        aF[m][ks] = frag(sa, wr * (BM_ / 2) + m * 16 + r16, ks * 32 + hk * 8);
#pragma unroll
    for (int n = 0; n < 2; ++n)
#pragma unroll
      for (int ks = 0; ks < 2; ++ks)
        bF0[n][ks] = frag(sb, wc * 64 + n * 16 + r16, ks * 32 + hk * 8);
    __builtin_amdgcn_s_barrier();
    __builtin_amdgcn_s_setprio(1);
#pragma unroll
    for (int ks = 0; ks < 2; ++ks)
#pragma unroll
      for (int m = 0; m < MQ; ++m)
#pragma unroll
        for (int n = 0; n < 2; ++n)
          acc[m][n] = __builtin_amdgcn_mfma_f32_16x16x32_bf16(bF0[n][ks], aF[m][ks], acc[m][n], 0, 0, 0);
    __builtin_amdgcn_s_setprio(0);
    __builtin_amdgcn_s_barrier();

    // ---- P1: read b-half1; MFMA Q(m-lo, n2-3) ----
#pragma unroll
    for (int n = 0; n < 2; ++n)
#pragma unroll
      for (int ks = 0; ks < 2; ++ks)
        bF1[n][ks] = frag(sb, wc * 64 + (2 + n) * 16 + r16, ks * 32 + hk * 8);
    __builtin_amdgcn_s_barrier();
    __builtin_amdgcn_s_setprio(1);
#pragma unroll
    for (int ks = 0; ks < 2; ++ks)
#pragma unroll
      for (int m = 0; m < MQ; ++m)
#pragma unroll
        for (int n = 0; n < 2; ++n)
          acc[m][2 + n] = __builtin_amdgcn_mfma_f32_16x16x32_bf16(bF1[n][ks], aF[m][ks], acc[m][2 + n], 0, 0, 0);
    __builtin_amdgcn_s_setprio(0);
    __builtin_amdgcn_s_barrier();

    // ---- P2: read a-half1; stage B(t+2); MFMA Q(m-hi, n2-3) ----
#pragma unroll
    for (int m = 0; m < MQ; ++m)
#pragma unroll
      for (int ks = 0; ks < 2; ++ks)
        aF[m][ks] = frag(sa, wr * (BM_ / 2) + (MQ + m) * 16 + r16, ks * 32 + hk * 8);
    if (pf) stageB(cb, kt + 2);
    __builtin_amdgcn_s_barrier();
    __builtin_amdgcn_s_setprio(1);
#pragma unroll
    for (int ks = 0; ks < 2; ++ks)
#pragma unroll
      for (int m = 0; m < MQ; ++m)
#pragma unroll
        for (int n = 0; n < 2; ++n)
          acc[MQ + m][2 + n] = __builtin_amdgcn_mfma_f32_16x16x32_bf16(bF1[n][ks], aF[m][ks], acc[MQ + m][2 + n], 0, 0, 0);
    __builtin_amdgcn_s_setprio(0);
    __builtin_amdgcn_s_barrier();

    // ---- P3: stage A(t+2); MFMA Q(m-hi, n0-1); counted wait ----
    if (pf) stageA(cb, kt + 2);
    __builtin_amdgcn_s_setprio(1);
#pragma unroll
    for (int ks = 0; ks < 2; ++ks)
#pragma unroll
      for (int m = 0; m < MQ; ++m)
#pragma unroll
        for (int n = 0; n < 2; ++n)
          acc[MQ + m][n] = __builtin_amdgcn_mfma_f32_16x16x32_bf16(bF0[n][ks], aF[m][ks], acc[MQ + m][n], 0, 0, 0);
    __builtin_amdgcn_s_setprio(0);
    if (pf) {
      if constexpr (BM_ == 256) asm volatile("s_waitcnt vmcnt(8)" ::: "memory");
      else                      asm volatile("s_waitcnt vmcnt(6)" ::: "memory");
    } else if (kt + 1 < nt) {
      asm volatile("s_waitcnt vmcnt(0)" ::: "memory");
    }
    __builtin_amdgcn_s_barrier();
  }

  // ---- epilogue ----
  bf16* Cp = C;
  const float* bp = bias;
  int ldc = N, colb = col0;
  if constexpr (SPLIT3) {
    int grp = col0 >> 10;
    Cp = grp == 0 ? C : (grp == 1 ? C2 : C3);
    bp = grp == 0 ? bias : (grp == 1 ? bias2 : bias3);
    ldc = 1024;
    colb = col0 & 1023;
  }
#pragma unroll
  for (int m = 0; m < MH; ++m) {
    int row = row0 + wr * (BM_ / 2) + m * 16 + r16;
#pragma unroll
    for (int n = 0; n < 4; ++n) {
      int col = colb + wc * 64 + n * 16 + hk * 4;
      f32x4 b4 = *(const f32x4*)&bp[col];
      f32x4 v;
#pragma unroll
      for (int r = 0; r < 4; ++r) v[r] = acc[m][n][r] + b4[r];
      if (RES == 1) {
        f32x4 rr = *(const f32x4*)&resf[(size_t)row * ldc + col];
#pragma unroll
        for (int r = 0; r < 4; ++r) v[r] += rr[r];
      }
      if (RES == 2) {
        bf16x4 rb = *(const bf16x4*)&resb[(size_t)row * ldc + col];
#pragma unroll
        for (int r = 0; r < 4; ++r) v[r] += (float)rb[r];
      }
      bf16x4 o;
#pragma unroll
      for (int r = 0; r < 4; ++r) {
        float x = v[r];
        if (GELU) x = gelu_fast(x);
        o[r] = (bf16)x;
      }
      *(bf16x4*)&Cp[(size_t)row * ldc + col] = o;
    }
  }
}

// ---------------------------------------------------------------- 2-phase GEMM (FFN-down)
// BM=128, BN=256, BK=64; bf16 residual; deep-K specialization.
// 2 phases/K-tile (16 MFMA each, 4 barriers/tile vs gemm_c's 8) to cut
// rendezvous overhead at 64 K-tiles. 3 LDS buffers (144 KiB) so staging
// tile t+2 targets a buffer last read at t-1 (sealed by t-1's final
// barrier) -- resolves the 2-phase same-buffer hazard. vmcnt(6) per tile
// completes t+1 (FIFO-oldest), leaves t+2 in flight (T4 never-drain).
__global__ __launch_bounds__(512) void gemm_d(
    const bf16* __restrict__ A, const bf16* __restrict__ BT,
    const float* __restrict__ bias, const bf16* __restrict__ resb,
    bf16* __restrict__ C, int M, int N, int K) {
  __shared__ alignas(16) bf16 sA[3][128 * 64];   // 48 KiB
  __shared__ alignas(16) bf16 sB[3][256 * 64];   // 96 KiB

  const int tid = threadIdx.x;
  const int lane = tid & 63, wv = tid >> 6;
  const int wr = wv >> 2, wc = wv & 3;       // 2 x 4 wave grid; wave tile 64x64
  const int r16 = lane & 15, hk = lane >> 4;

  const int nbn = N >> 8;
  const int cpx = gridDim.x >> 3;            // grid % 8 == 0
  const int swz = ((int)blockIdx.x & 7) * cpx + ((int)blockIdx.x >> 3);
  const int row0 = (swz / nbn) * 128, col0 = (swz % nbn) << 8;

  const bf16* Ab = A + (size_t)row0 * K;
  const bf16* Bb = BT + (size_t)col0 * K;

  const bf16* gA[2];
  const bf16* gB[4];
#pragma unroll
  for (int l = 0; l < 2; ++l) {
    int g = l * 512 + tid, r = g >> 3, p = g & 7;
    gA[l] = Ab + (size_t)r * K + ((p ^ (r & 7)) << 3);
  }
#pragma unroll
  for (int l = 0; l < 4; ++l) {
    int g = l * 512 + tid, r = g >> 3, p = g & 7;
    gB[l] = Bb + (size_t)r * K + ((p ^ (r & 7)) << 3);
  }

  auto stage = [&](int buf, int kt) {
    const size_t ko = (size_t)kt << 6;
#pragma unroll
    for (int l = 0; l < 2; ++l)
      gload_lds16(gA[l] + ko, &sA[buf][(l * 512 + tid) * 8]);
#pragma unroll
    for (int l = 0; l < 4; ++l)
      gload_lds16(gB[l] + ko, &sB[buf][(l * 512 + tid) * 8]);
  };
  auto frag = [&](const bf16* s, int row, int kc) -> bf16x8 {
    return *(const bf16x8*)(s + row * 64 + (kc ^ ((row & 7) * 8)));
  };

  f32x4 acc[4][4] = {};
  bf16x8 aF[4][2], bF0[2][2], bF1[2][2];

  const int nt = K >> 6;
  stage(0, 0);
  stage(1, 1);
  asm volatile("s_waitcnt vmcnt(6)" ::: "memory");   // drain tile 0, keep tile 1
  __builtin_amdgcn_s_barrier();

  int cur = 0;
  for (int kt = 0; kt < nt; ++kt) {
    const bf16* sa = &sA[cur][0];
    const bf16* sb = &sB[cur][0];
    const int nx2 = (cur + 2 >= 3) ? cur - 1 : cur + 2;   // (kt+2)%3
    const bool pf = (kt + 2 < nt);

    // ---- P0: read aF(all 4 m) + bF0; MFMA (m0-3, n0-1) ----
#pragma unroll
    for (int m = 0; m < 4; ++m)
#pragma unroll
      for (int ks = 0; ks < 2; ++ks)
        aF[m][ks] = frag(sa, wr * 64 + m * 16 + r16, ks * 32 + hk * 8);
#pragma unroll
    for (int n = 0; n < 2; ++n)
#pragma unroll
      for (int ks = 0; ks < 2; ++ks)
        bF0[n][ks] = frag(sb, wc * 64 + n * 16 + r16, ks * 32 + hk * 8);
    __builtin_amdgcn_s_barrier();
    __builtin_amdgcn_s_setprio(1);
#pragma unroll
    for (int ks = 0; ks < 2; ++ks)
#pragma unroll
      for (int m = 0; m < 4; ++m)
#pragma unroll
        for (int n = 0; n < 2; ++n)
          acc[m][n] = __builtin_amdgcn_mfma_f32_16x16x32_bf16(bF0[n][ks], aF[m][ks], acc[m][n], 0, 0, 0);
    __builtin_amdgcn_s_setprio(0);
    __builtin_amdgcn_s_barrier();

    // ---- P1: read bF1; stage tile t+2 into buf (kt+2)%3; MFMA (m0-3, n2-3) ----
#pragma unroll
    for (int n = 0; n < 2; ++n)
#pragma unroll
      for (int ks = 0; ks < 2; ++ks)
        bF1[n][ks] = frag(sb, wc * 64 + (2 + n) * 16 + r16, ks * 32 + hk * 8);
    if (pf) stage(nx2, kt + 2);
    __builtin_amdgcn_s_barrier();
    __builtin_amdgcn_s_setprio(1);
#pragma unroll
    for (int ks = 0; ks < 2; ++ks)
#pragma unroll
      for (int m = 0; m < 4; ++m)
#pragma unroll
        for (int n = 0; n < 2; ++n)
          acc[m][2 + n] = __builtin_amdgcn_mfma_f32_16x16x32_bf16(bF1[n][ks], aF[m][ks], acc[m][2 + n], 0, 0, 0);
    __builtin_amdgcn_s_setprio(0);
    if (pf) {
      asm volatile("s_waitcnt vmcnt(6)" ::: "memory");  // t+1 done; t+2 in flight
    } else if (kt + 1 < nt) {
      asm volatile("s_waitcnt vmcnt(0)" ::: "memory");
    }
    __builtin_amdgcn_s_barrier();
    cur = (cur + 1 == 3) ? 0 : cur + 1;
  }

  // ---- epilogue: bias + bf16 residual ----
#pragma unroll
  for (int m = 0; m < 4; ++m) {
    int row = row0 + wr * 64 + m * 16 + r16;
#pragma unroll
    for (int n = 0; n < 4; ++n) {
      int col = col0 + wc * 64 + n * 16 + hk * 4;
      f32x4 b4 = *(const f32x4*)&bias[col];
      bf16x4 rb = *(const bf16x4*)&resb[(size_t)row * N + col];
      bf16x4 o;
#pragma unroll
      for (int r = 0; r < 4; ++r)
        o[r] = (bf16)(acc[m][n][r] + b4[r] + (float)rb[r]);
      *(bf16x4*)&C[(size_t)row * N + col] = o;
    }
  }
}

// ---------------------------------------------------------------- attention
// one block per (b,h); L=64, dh=64. ctx may alias q.
__global__ __launch_bounds__(256) void attn_k(
    const bf16* q, const bf16* __restrict__ k,
    const bf16* __restrict__ v, const float* __restrict__ rel,
    bf16* ctx) {
  __shared__ alignas(16) bf16 lQ[64 * 64];
  __shared__ alignas(16) bf16 lK[64 * 64];
  __shared__ alignas(16) bf16 lVt[64 * 64];
  __shared__ alignas(16) bf16 lP[4][16 * 64];
  __shared__ float lrel[128];

  const int bh = blockIdx.x;
  const int b = bh >> 4, h = bh & 15;
  const int tid = threadIdx.x;
  const size_t base = (size_t)(b * 64) * DMODEL + h * 64;

#pragma unroll
  for (int i = 0; i < 2; ++i) {
    int j = (tid >> 3) + i * 32;
    int d0 = (tid & 7) * 8;
    *(bf16x8*)&lQ[j * 64 + d0] = *(const bf16x8*)(q + base + (size_t)j * DMODEL + d0);
    *(bf16x8*)&lK[j * 64 + d0] = *(const bf16x8*)(k + base + (size_t)j * DMODEL + d0);
    bf16x8 vvv = *(const bf16x8*)(v + base + (size_t)j * DMODEL + d0);
#pragma unroll
    for (int u = 0; u < 8; ++u) lVt[(d0 + u) * 64 + j] = vvv[u];
  }
  if (tid < 127) lrel[tid] = rel[h * 127 + tid];
  __syncthreads();

  const int lane = tid & 63, w = tid >> 6;
  const int r16 = lane & 15, hk = lane >> 4;

  f32x4 s[4] = {};
#pragma unroll
  for (int dstep = 0; dstep < 2; ++dstep) {
    bf16x8 aq = *(const bf16x8*)&lQ[(w * 16 + r16) * 64 + dstep * 32 + hk * 8];
#pragma unroll
    for (int n = 0; n < 4; ++n) {
      bf16x8 bk_ = *(const bf16x8*)&lK[(n * 16 + r16) * 64 + dstep * 32 + hk * 8];
      s[n] = __builtin_amdgcn_mfma_f32_16x16x32_bf16(aq, bk_, s[n], 0, 0, 0);
    }
  }

  float p[16];
#pragma unroll
  for (int n = 0; n < 4; ++n)
#pragma unroll
    for (int r = 0; r < 4; ++r) {
      int i = w * 16 + hk * 4 + r;
      int j = n * 16 + r16;
      p[n * 4 + r] = s[n][r] * 0.125f + lrel[i - j + 63];
    }
#pragma unroll
  for (int r = 0; r < 4; ++r) {
    float m = fmaxf(fmaxf(p[r], p[4 + r]), fmaxf(p[8 + r], p[12 + r]));
#pragma unroll
    for (int off = 1; off < 16; off <<= 1) m = fmaxf(m, __shfl_xor(m, off));
    float sum = 0.f;
#pragma unroll
    for (int n = 0; n < 4; ++n) {
      p[n * 4 + r] = __expf(p[n * 4 + r] - m);
      sum += p[n * 4 + r];
    }
#pragma unroll
    for (int off = 1; off < 16; off <<= 1) sum += __shfl_xor(sum, off);
    float inv = 1.0f / sum;
#pragma unroll
    for (int n = 0; n < 4; ++n) p[n * 4 + r] *= inv;
  }
#pragma unroll
  for (int n = 0; n < 4; ++n)
#pragma unroll
    for (int r = 0; r < 4; ++r)
      lP[w][(hk * 4 + r) * 64 + n * 16 + r16] = (bf16)p[n * 4 + r];
  __syncthreads();

  f32x4 o[4] = {};
#pragma unroll
  for (int ks = 0; ks < 2; ++ks) {
    bf16x8 ap = *(const bf16x8*)&lP[w][r16 * 64 + ks * 32 + hk * 8];
#pragma unroll
    for (int n = 0; n < 4; ++n) {
      bf16x8 bv_ = *(const bf16x8*)&lVt[(n * 16 + r16) * 64 + ks * 32 + hk * 8];
      o[n] = __builtin_amdgcn_mfma_f32_16x16x32_bf16(ap, bv_, o[n], 0, 0, 0);
    }
  }
#pragma unroll
  for (int n = 0; n < 4; ++n)
#pragma unroll
    for (int r = 0; r < 4; ++r) {
      int trow = b * 64 + w * 16 + hk * 4 + r;
      ctx[(size_t)trow * DMODEL + h * 64 + n * 16 + r16] = (bf16)o[n][r];
    }
}

// ---------------------------------------------------------------- layernorm
template <int F32OUT>
__global__ __launch_bounds__(256) void layernorm_k(
    const bf16* __restrict__ x, const float* __restrict__ g,
    const float* __restrict__ be, bf16* __restrict__ ob,
    float* __restrict__ of) {
  int row = blockIdx.x * 4 + (threadIdx.x >> 6);
  int lane = threadIdx.x & 63;
  const bf16* xr = x + (size_t)row * DMODEL + lane * 16;
  bf16x8 v0 = *(const bf16x8*)xr;
  bf16x8 v1 = *(const bf16x8*)(xr + 8);
  float f[16];
#pragma unroll
  for (int j = 0; j < 8; ++j) { f[j] = (float)v0[j]; f[8 + j] = (float)v1[j]; }
  float s = 0.f, sq = 0.f;
#pragma unroll
  for (int j = 0; j < 16; ++j) { s += f[j]; sq += f[j] * f[j]; }
#pragma unroll
  for (int off = 1; off < 64; off <<= 1) {
    s += __shfl_xor(s, off);
    sq += __shfl_xor(sq, off);
  }
  float mean = s * (1.0f / DMODEL);
  float var = sq * (1.0f / DMODEL) - mean * mean;
  float rstd = rsqrtf(var + 1e-5f);
  const float* gp = g + lane * 16;
  const float* bp = be + lane * 16;
  if (F32OUT) {
    float* op = of + (size_t)row * DMODEL + lane * 16;
#pragma unroll
    for (int j = 0; j < 16; ++j)
      op[j] = (f[j] - mean) * rstd * gp[j] + bp[j];
  } else {
    bf16x8 o0, o1;
#pragma unroll
    for (int j = 0; j < 8; ++j) {
      o0[j] = (bf16)((f[j] - mean) * rstd * gp[j] + bp[j]);
      o1[j] = (bf16)((f[8 + j] - mean) * rstd * gp[8 + j] + bp[8 + j]);
    }
    bf16* op = ob + (size_t)row * DMODEL + lane * 16;
    *(bf16x8*)op = o0;
    *(bf16x8*)(op + 8) = o1;
  }
}

// ---------------------------------------------------------------- launch
extern "C" void kernel_launch(void* const* d_in, const int* in_sizes, int n_in,
                              void* d_out, int out_size, void* d_ws, size_t ws_size,
                              hipStream_t stream) {
  (void)in_sizes; (void)n_in; (void)out_size;
  const float* src = (const float*)d_in[0];
  const float* Wq  = (const float*)d_in[1];
  const float* bq  = (const float*)d_in[2];
  const float* Wk  = (const float*)d_in[3];
  const float* bk  = (const float*)d_in[4];
  const float* Wv  = (const float*)d_in[5];
  const float* bv  = (const float*)d_in[6];
  const float* Wo  = (const float*)d_in[7];
  const float* bo  = (const float*)d_in[8];
  const float* rel = (const float*)d_in[9];
  const float* W1  = (const float*)d_in[10];
  const float* b1  = (const float*)d_in[11];
  const float* W2  = (const float*)d_in[12];
  const float* b2  = (const float*)d_in[13];
  const float* g1  = (const float*)d_in[14];
  const float* be1 = (const float*)d_in[15];
  const float* g2  = (const float*)d_in[16];
  const float* be2 = (const float*)d_in[17];

  // ws plan: REGION0 = ws[0:64MiB] (srcb+qb -> hbuf -> lnout);
  // weights ws[64:88MiB] (WqT/WkT/WvT contiguous => fused QKV B matrix);
  // y2 in ws[88:120MiB] when ws_size allows, else d_out + copy-out.
  char* ws = (char*)d_ws;
  const size_t MiB = 1ull << 20;
  bf16* srcb = (bf16*)(ws + 0 * MiB);
  bf16* qb   = (bf16*)(ws + 32 * MiB);
  bf16* WqT  = (bf16*)(ws + 64 * MiB);   // [3072][1024] fused: Wq|Wk|Wv
  bf16* WkT  = (bf16*)(ws + 66 * MiB);
  bf16* WvT  = (bf16*)(ws + 68 * MiB);
  bf16* WoT  = (bf16*)(ws + 70 * MiB);
  bf16* W1T  = (bf16*)(ws + 72 * MiB);
  bf16* W2T  = (bf16*)(ws + 80 * MiB);
  bf16* hbuf = (bf16*)(ws + 0 * MiB);
  float* lnout = (float*)(ws + 0 * MiB);
  bf16* kb = (bf16*)d_out;
  bf16* vb = (bf16*)((char*)d_out + 32 * MiB);
  bf16* y1 = kb;
  bf16* xb = vb;
  const bool bigws = (ws_size >= 121 * MiB);
  bf16* y2 = bigws ? (bf16*)(ws + 88 * MiB) : kb;

  cvt_copy<<<(N_TOK * DMODEL) / 2048, 256, 0, stream>>>(src, srcb);
  dim3 tb(32, 8);
  convt<<<dim3(32, 32), tb, 0, stream>>>(Wq, WqT, 1024, 1024);
  convt<<<dim3(32, 32), tb, 0, stream>>>(Wk, WkT, 1024, 1024);
  convt<<<dim3(32, 32), tb, 0, stream>>>(Wv, WvT, 1024, 1024);
  convt<<<dim3(32, 32), tb, 0, stream>>>(Wo, WoT, 1024, 1024);
  convt<<<dim3(128, 32), tb, 0, stream>>>(W1, W1T, 1024, 4096);
  convt<<<dim3(32, 128), tb, 0, stream>>>(W2, W2T, 4096, 1024);

  // fused QKV: one GEMM, N=3072 (WqT/WkT/WvT contiguous), split outputs
  const int gQKV3 = (N_TOK / 256) * (3072 / 256);   // 64*12 = 768
  gemm_c<256, 0, 0, 1><<<gQKV3, 512, 0, stream>>>(
      srcb, WqT, bq, bk, bv, nullptr, nullptr, qb, kb, vb, N_TOK, 3072, DMODEL);

  attn_k<<<256 * NHEAD, 256, 0, stream>>>(qb, kb, vb, rel, qb);

  const int gD = (N_TOK / 256) * (DMODEL / 256);    // 256
  // y1 = ctx @ Wo + bo + src (fp32 residual) -> DO0
  gemm_c<256, 1, 0, 0><<<gD, 512, 0, stream>>>(
      qb, WoT, bo, nullptr, nullptr, src, nullptr, y1, nullptr, nullptr, N_TOK, DMODEL, DMODEL);
  // x = LN1(y1) -> DO1
  layernorm_k<0><<<N_TOK / 4, 256, 0, stream>>>(y1, g1, be1, xb, nullptr);

  // FFN in 2 chunks of 8192 rows; h (8192x4096 bf16 = 64 MiB) in REGION0
  const int CH = 8192;
  const int gF1 = (CH / 256) * (FDIM / 256);     // 32*16 = 512
  const int gF2 = (CH / 128) * (DMODEL / 256);   // 64*4  = 256  (BM=128, 2-phase)
  for (int c = 0; c < 2; ++c) {
    const bf16* xc = xb + (size_t)c * CH * DMODEL;
    bf16* yc = y2 + (size_t)c * CH * DMODEL;
    gemm_c<256, 0, 1, 0><<<gF1, 512, 0, stream>>>(
        xc, W1T, b1, nullptr, nullptr, nullptr, nullptr, hbuf, nullptr, nullptr, CH, FDIM, DMODEL);
    gemm_d<<<gF2, 512, 0, stream>>>(hbuf, W2T, b2, xc, yc, CH, DMODEL, FDIM);
  }
  if (bigws) {
    layernorm_k<1><<<N_TOK / 4, 256, 0, stream>>>(y2, g2, be2, nullptr, (float*)d_out);
  } else {
    layernorm_k<1><<<N_TOK / 4, 256, 0, stream>>>(y2, g2, be2, nullptr, lnout);
    hipMemcpyAsync(d_out, lnout, (size_t)N_TOK * DMODEL * 4, hipMemcpyDeviceToDevice, stream);
  }
}